// Round 1
// baseline (878.631 us; speedup 1.0000x reference)
//
#include <hip/hip_runtime.h>
#include <hip/hip_bf16.h>

#define NN 8192
#define DD 384
#define NE 262144
#define NR 4
#define NL 2
#define NB 64

// ---------------- BatchNorm stats ----------------
__global__ void k_colstats(const float* __restrict__ x, float* __restrict__ musum,
                           float* __restrict__ msqsum) {
  int c = threadIdx.x;            // 384
  int r0 = blockIdx.x * 128;      // 64 blocks
  float s = 0.f, s2 = 0.f;
  for (int r = 0; r < 128; ++r) {
    float v = x[(r0 + r) * DD + c];
    s += v; s2 += v * v;
  }
  atomicAdd(&musum[c], s);
  atomicAdd(&msqsum[c], s2);
}

__global__ void k_finstats(const float* __restrict__ musum, const float* __restrict__ msqsum,
                           float* __restrict__ mu, float* __restrict__ rstd) {
  int c = threadIdx.x;
  float m = musum[c] * (1.f / NN);
  float v = msqsum[c] * (1.f / NN) - m * m;
  mu[c] = m;
  rstd[c] = rsqrtf(v + 1e-5f);
}

// h = gamma*(x-mu)*rstd + beta ; norminv = 1/||h||_row
__global__ void k_bn(const float* __restrict__ x, const float* __restrict__ gamma,
                     const float* __restrict__ beta, const float* __restrict__ mu,
                     const float* __restrict__ rstd, float* __restrict__ h,
                     float* __restrict__ ninv) {
  int n = blockIdx.x;
  int t = threadIdx.x;  // 64
  float ss = 0.f;
#pragma unroll
  for (int i = 0; i < 6; ++i) {
    int c = t + i * 64;
    float v = gamma[c] * (x[n * DD + c] - mu[c]) * rstd[c] + beta[c];
    h[n * DD + c] = v;
    ss += v * v;
  }
#pragma unroll
  for (int m = 32; m; m >>= 1) ss += __shfl_xor(ss, m, 64);
  if (t == 0) ninv[n] = rsqrtf(ss);
}

// ---------------- degree histograms ----------------
__global__ void k_counts(const int* __restrict__ ei, const int* __restrict__ et,
                         int* __restrict__ c_tot, int* __restrict__ c_rel) {
  int e = blockIdx.x * blockDim.x + threadIdx.x;
  if (e >= NE) return;
  int dst = ei[NE + e];
  int r = et[e];
  atomicAdd(&c_tot[dst], 1);
  atomicAdd(&c_rel[dst * NR + r], 1);
}

// exclusive scan of c_tot (8192) -> row_ptr[8193], cursor copy
__global__ void k_scan(const int* __restrict__ c_tot, int* __restrict__ row_ptr,
                       int* __restrict__ cursor) {
  __shared__ int part[1024];
  int t = threadIdx.x;
  int base = t * 8;
  int v[8]; int s = 0;
#pragma unroll
  for (int i = 0; i < 8; ++i) { v[i] = c_tot[base + i]; s += v[i]; }
  part[t] = s;
  __syncthreads();
  for (int off = 1; off < 1024; off <<= 1) {
    int add = (t >= off) ? part[t - off] : 0;
    __syncthreads();
    part[t] += add;
    __syncthreads();
  }
  int run = (t == 0) ? 0 : part[t - 1];
  if (t == 0) row_ptr[0] = 0;
#pragma unroll
  for (int i = 0; i < 8; ++i) {
    cursor[base + i] = run;
    run += v[i];
    row_ptr[base + i + 1] = run;
  }
}

// ---------------- edge cosine weights ----------------
__global__ void k_we(const float* __restrict__ h, const float* __restrict__ ninv,
                     const int* __restrict__ ei, float* __restrict__ w_e) {
  int lane = threadIdx.x & 63;
  int wv = blockIdx.x * (blockDim.x >> 6) + (threadIdx.x >> 6);
  int nw = gridDim.x * (blockDim.x >> 6);
  for (int e = wv; e < NE; e += nw) {
    int s = ei[e], d = ei[NE + e];
    const float4* hs = (const float4*)(h + s * DD);
    const float4* hd = (const float4*)(h + d * DD);
    float4 a = hs[lane], b = hd[lane];
    float acc = a.x * b.x + a.y * b.y + a.z * b.z + a.w * b.w;
    if (lane < 32) {
      float4 a2 = hs[64 + lane], b2 = hd[64 + lane];
      acc += a2.x * b2.x + a2.y * b2.y + a2.z * b2.z + a2.w * b2.w;
    }
#pragma unroll
    for (int m = 32; m; m >>= 1) acc += __shfl_xor(acc, m, 64);
    if (lane == 0) w_e[e] = acc * ninv[s] * ninv[d];
  }
}

// ---------------- CSR fill ----------------
__global__ void k_fill(const int* __restrict__ ei, const int* __restrict__ et,
                       const float* __restrict__ w_e, int* __restrict__ cursor,
                       int* __restrict__ meta, float* __restrict__ wsort) {
  int e = blockIdx.x * blockDim.x + threadIdx.x;
  if (e >= NE) return;
  int src = ei[e], dst = ei[NE + e];
  int pos = atomicAdd(&cursor[dst], 1);
  meta[pos] = src | (et[e] << 13);
  wsort[pos] = w_e[e];
}

// ---------------- per-relation aggregation of h ----------------
// Agg[n][r*384+d] = (1/(nc_r*max(c_r,1))) * sum_{e->n, rel=r} w_e * h[src][d]
// SC[n][r]       = (1/(nc_r*max(c_r,1))) * sum w_e
__global__ void k_aggrel(const float* __restrict__ h, const int* __restrict__ row_ptr,
                         const int* __restrict__ meta, const float* __restrict__ wsort,
                         const int* __restrict__ c_rel, const float* __restrict__ nc,
                         float* __restrict__ Agg, float* __restrict__ SC, int layer) {
  int n = blockIdx.x;
  int t = threadIdx.x;  // 128
  float a0x = 0, a0y = 0, a0z = 0, a1x = 0, a1y = 0, a1z = 0;
  float a2x = 0, a2y = 0, a2z = 0, a3x = 0, a3y = 0, a3z = 0;
  float s0 = 0, s1 = 0, s2 = 0, s3 = 0;
  int beg = row_ptr[n], end = row_ptr[n + 1];
  for (int e = beg; e < end; ++e) {
    int m = meta[e];
    float w = wsort[e];
    int src = m & 8191;
    int r = m >> 13;
    const float* hs = h + src * DD;
    float vx = hs[t], vy = hs[t + 128], vz = hs[t + 256];
    if (r == 0)      { a0x += w * vx; a0y += w * vy; a0z += w * vz; s0 += w; }
    else if (r == 1) { a1x += w * vx; a1y += w * vy; a1z += w * vz; s1 += w; }
    else if (r == 2) { a2x += w * vx; a2y += w * vy; a2z += w * vz; s2 += w; }
    else             { a3x += w * vx; a3y += w * vy; a3z += w * vz; s3 += w; }
  }
  float f[4];
#pragma unroll
  for (int r = 0; r < 4; ++r) {
    int c = c_rel[n * 4 + r];
    f[r] = 1.f / (nc[layer * 4 + r] * (float)(c > 1 ? c : 1));
  }
  float* an = Agg + (size_t)n * 1536;
  an[0 * 384 + t] = a0x * f[0]; an[0 * 384 + t + 128] = a0y * f[0]; an[0 * 384 + t + 256] = a0z * f[0];
  an[1 * 384 + t] = a1x * f[1]; an[1 * 384 + t + 128] = a1y * f[1]; an[1 * 384 + t + 256] = a1z * f[1];
  an[2 * 384 + t] = a2x * f[2]; an[2 * 384 + t + 128] = a2y * f[2]; an[2 * 384 + t + 256] = a2z * f[2];
  an[3 * 384 + t] = a3x * f[3]; an[3 * 384 + t + 128] = a3y * f[3]; an[3 * 384 + t + 256] = a3z * f[3];
  if (t == 0) {
    SC[n * 4 + 0] = s0 * f[0]; SC[n * 4 + 1] = s1 * f[1];
    SC[n * 4 + 2] = s2 * f[2]; SC[n * 4 + 3] = s3 * f[3];
  }
}

// ---------------- MP mean aggregation of rel_out ----------------
// B1[n][0:384] = (sum_{e->n} B1[src][384:768]) / max(deg,1)
__global__ void k_aggmp(float* __restrict__ B1, const int* __restrict__ row_ptr,
                        const int* __restrict__ meta) {
  int n = blockIdx.x;
  int t = threadIdx.x;  // 128
  float ax = 0, ay = 0, az = 0;
  int beg = row_ptr[n], end = row_ptr[n + 1];
  for (int e = beg; e < end; ++e) {
    int src = meta[e] & 8191;
    const float* rs = B1 + (size_t)src * 768 + 384;
    ax += rs[t]; ay += rs[t + 128]; az += rs[t + 256];
  }
  float inv = (end > beg) ? 1.f / (float)(end - beg) : 0.f;
  float* o = B1 + (size_t)n * 768;
  o[t] = ax * inv; o[t + 128] = ay * inv; o[t + 256] = az * inv;
}

// ---------------- weight packing ----------------
__global__ void k_pack1(const float* __restrict__ W_rel, float* __restrict__ Wcat, int layer) {
  int idx = blockIdx.x * blockDim.x + threadIdx.x;  // 384*1536
  if (idx >= 384 * 1536) return;
  int i = idx / 1536, kk = idx - i * 1536;
  int r = kk / 384, k = kk - r * 384;
  Wcat[idx] = W_rel[(((size_t)(layer * NR + r) * DD) + i) * DD + k];
}
__global__ void k_pack2(const float* __restrict__ W_msg, const float* __restrict__ W_self,
                        float* __restrict__ Wcat2, int layer) {
  int idx = blockIdx.x * blockDim.x + threadIdx.x;  // 384*768
  if (idx >= 384 * 768) return;
  int i = idx / 768, kk = idx - i * 768;
  Wcat2[idx] = (kk < 384) ? W_msg[((size_t)layer * DD + i) * DD + kk]
                          : W_self[((size_t)layer * DD + i) * DD + kk - 384];
}

// ---------------- fp32 NT GEMM: C[8192 x 384] = A[8192 x K] * Bp[384 x K]^T ----------------
// MODE 0: epilogue adds SC·b_rel, relu, stores to B1[:,384:768]
// MODE 1: epilogue h = relu(acc + deg?b_msg + b_self) + h
template <int MODE>
__global__ __launch_bounds__(256) void k_gemm(
    const float* __restrict__ A, int K, const float* __restrict__ Bp,
    const float* __restrict__ SC, const float* __restrict__ brel_l,
    const float* __restrict__ bmsg_l, const float* __restrict__ bself_l,
    const int* __restrict__ row_ptr, float* __restrict__ h, float* __restrict__ Cout) {
  __shared__ float As[32 * 68];
  __shared__ float Bs[32 * 68];
  int tid = threadIdx.x;
  int tx = tid & 15, ty = tid >> 4;
  int bm = blockIdx.x, bn = blockIdx.y;
  int r = tid >> 3;
  int kq = (tid & 7) << 2;
  const float* Ag = A + (size_t)(bm * 64 + r) * K + kq;
  const float* Bg = Bp + (size_t)(bn * 64 + r) * K + kq;
  float acc[4][4] = {};
  for (int k0 = 0; k0 < K; k0 += 32) {
    float4 av0 = *(const float4*)(Ag + k0);
    float4 av1 = *(const float4*)(Ag + k0 + (size_t)32 * K);
    float4 bv0 = *(const float4*)(Bg + k0);
    float4 bv1 = *(const float4*)(Bg + k0 + (size_t)32 * K);
    __syncthreads();
    As[(kq + 0) * 68 + r] = av0.x; As[(kq + 1) * 68 + r] = av0.y;
    As[(kq + 2) * 68 + r] = av0.z; As[(kq + 3) * 68 + r] = av0.w;
    As[(kq + 0) * 68 + r + 32] = av1.x; As[(kq + 1) * 68 + r + 32] = av1.y;
    As[(kq + 2) * 68 + r + 32] = av1.z; As[(kq + 3) * 68 + r + 32] = av1.w;
    Bs[(kq + 0) * 68 + r] = bv0.x; Bs[(kq + 1) * 68 + r] = bv0.y;
    Bs[(kq + 2) * 68 + r] = bv0.z; Bs[(kq + 3) * 68 + r] = bv0.w;
    Bs[(kq + 0) * 68 + r + 32] = bv1.x; Bs[(kq + 1) * 68 + r + 32] = bv1.y;
    Bs[(kq + 2) * 68 + r + 32] = bv1.z; Bs[(kq + 3) * 68 + r + 32] = bv1.w;
    __syncthreads();
#pragma unroll
    for (int k = 0; k < 32; ++k) {
      float4 a = *(const float4*)&As[k * 68 + ty * 4];
      float4 b = *(const float4*)&Bs[k * 68 + tx * 4];
      acc[0][0] += a.x * b.x; acc[0][1] += a.x * b.y; acc[0][2] += a.x * b.z; acc[0][3] += a.x * b.w;
      acc[1][0] += a.y * b.x; acc[1][1] += a.y * b.y; acc[1][2] += a.y * b.z; acc[1][3] += a.y * b.w;
      acc[2][0] += a.z * b.x; acc[2][1] += a.z * b.y; acc[2][2] += a.z * b.z; acc[2][3] += a.z * b.w;
      acc[3][0] += a.w * b.x; acc[3][1] += a.w * b.y; acc[3][2] += a.w * b.z; acc[3][3] += a.w * b.w;
    }
  }
  int row0 = bm * 64 + ty * 4;
  int col0 = bn * 64 + tx * 4;
  if (MODE == 0) {
#pragma unroll
    for (int i = 0; i < 4; ++i) {
      int row = row0 + i;
      float4 sc = *(const float4*)&SC[row * 4];
      float4 o;
      float* op = &o.x;
#pragma unroll
      for (int j = 0; j < 4; ++j) {
        int col = col0 + j;
        float v = acc[i][j] + sc.x * brel_l[0 * 384 + col] + sc.y * brel_l[1 * 384 + col] +
                  sc.z * brel_l[2 * 384 + col] + sc.w * brel_l[3 * 384 + col];
        op[j] = fmaxf(v, 0.f);
      }
      *(float4*)&Cout[(size_t)row * 768 + 384 + col0] = o;
    }
  } else {
#pragma unroll
    for (int i = 0; i < 4; ++i) {
      int row = row0 + i;
      float bmul = (row_ptr[row + 1] > row_ptr[row]) ? 1.f : 0.f;
      float4 hv = *(const float4*)&h[(size_t)row * DD + col0];
      float* hp = &hv.x;
      float4 o;
      float* op = &o.x;
#pragma unroll
      for (int j = 0; j < 4; ++j) {
        int col = col0 + j;
        float v = acc[i][j] + bmul * bmsg_l[col] + bself_l[col];
        op[j] = fmaxf(v, 0.f) + hp[j];
      }
      *(float4*)&h[(size_t)row * DD + col0] = o;
    }
  }
}

// ---------------- final per-batch mean ----------------
__global__ void k_out(const float* __restrict__ h, float* __restrict__ out) {
  int b = blockIdx.x;   // 64
  int c = threadIdx.x;  // 384
  float s = 0.f;
  for (int j = 0; j < 128; ++j) s += h[(size_t)(b * 128 + j) * DD + c];
  out[b * DD + c] = s * (1.f / 128.f);
}

extern "C" void kernel_launch(void* const* d_in, const int* in_sizes, int n_in,
                              void* d_out, int out_size, void* d_ws, size_t ws_size,
                              hipStream_t stream) {
  const float* x      = (const float*)d_in[0];
  const int*   ei     = (const int*)d_in[1];
  const int*   et     = (const int*)d_in[2];
  const float* gamma  = (const float*)d_in[3];
  const float* beta   = (const float*)d_in[4];
  const float* W_rel  = (const float*)d_in[5];
  const float* b_rel  = (const float*)d_in[6];
  const float* nc     = (const float*)d_in[7];
  const float* W_msg  = (const float*)d_in[8];
  const float* b_msg  = (const float*)d_in[9];
  const float* W_self = (const float*)d_in[10];
  const float* b_self = (const float*)d_in[11];
  float* out = (float*)d_out;

  char* ws = (char*)d_ws;
  size_t off = 0;
  auto alloc = [&](size_t bytes) -> void* {
    void* p = ws + off;
    off = (off + bytes + 255) & ~(size_t)255;
    return p;
  };
  float* h      = (float*)alloc((size_t)NN * DD * 4);
  float* Agg    = (float*)alloc((size_t)NN * 1536 * 4);
  float* B1     = (float*)alloc((size_t)NN * 768 * 4);
  float* Wcat   = (float*)alloc((size_t)384 * 1536 * 4);
  float* Wcat2  = (float*)alloc((size_t)384 * 768 * 4);
  float* SC     = (float*)alloc((size_t)NN * 4 * 4);
  float* w_e    = (float*)alloc((size_t)NE * 4);
  int*   meta   = (int*)alloc((size_t)NE * 4);
  float* wsort  = (float*)alloc((size_t)NE * 4);
  int*   row_ptr= (int*)alloc((size_t)(NN + 1) * 4);
  int*   cursor = (int*)alloc((size_t)NN * 4);
  float* ninv   = (float*)alloc((size_t)NN * 4);
  char*  zb     = (char*)alloc(166912);  // musum|msqsum|c_tot|c_rel contiguous, zeroed
  float* musum  = (float*)(zb);
  float* msqsum = (float*)(zb + 1536);
  int*   c_tot  = (int*)(zb + 3072);
  int*   c_rel  = (int*)(zb + 35840);
  float* mu     = (float*)alloc(DD * 4);
  float* rstd   = (float*)alloc(DD * 4);

  hipMemsetAsync(zb, 0, 166912, stream);
  k_colstats<<<64, 384, 0, stream>>>(x, musum, msqsum);
  k_finstats<<<1, 384, 0, stream>>>(musum, msqsum, mu, rstd);
  k_bn<<<NN, 64, 0, stream>>>(x, gamma, beta, mu, rstd, h, ninv);
  k_counts<<<NE / 256, 256, 0, stream>>>(ei, et, c_tot, c_rel);
  k_scan<<<1, 1024, 0, stream>>>(c_tot, row_ptr, cursor);
  k_we<<<2048, 256, 0, stream>>>(h, ninv, ei, w_e);
  k_fill<<<NE / 256, 256, 0, stream>>>(ei, et, w_e, cursor, meta, wsort);

  for (int l = 0; l < NL; ++l) {
    k_pack1<<<(384 * 1536 + 255) / 256, 256, 0, stream>>>(W_rel, Wcat, l);
    k_pack2<<<(384 * 768 + 255) / 256, 256, 0, stream>>>(W_msg, W_self, Wcat2, l);
    k_aggrel<<<NN, 128, 0, stream>>>(h, row_ptr, meta, wsort, c_rel, nc, Agg, SC, l);
    k_gemm<0><<<dim3(128, 6), 256, 0, stream>>>(Agg, 1536, Wcat, SC, b_rel + l * NR * DD,
                                                nullptr, nullptr, nullptr, nullptr, B1);
    k_aggmp<<<NN, 128, 0, stream>>>(B1, row_ptr, meta);
    k_gemm<1><<<dim3(128, 6), 256, 0, stream>>>(B1, 768, Wcat2, nullptr, nullptr,
                                                b_msg + l * DD, b_self + l * DD, row_ptr, h,
                                                nullptr);
  }
  k_out<<<64, 384, 0, stream>>>(h, out);
}

// Round 2
// 521.907 us; speedup vs baseline: 1.6835x; 1.6835x over previous
//
#include <hip/hip_runtime.h>
#include <hip/hip_bf16.h>

#define NN 8192
#define DD 384
#define NE 262144
#define NR 4
#define NL 2
#define NB 64

typedef __attribute__((ext_vector_type(8))) short bf16x8;
typedef __attribute__((ext_vector_type(4))) float f32x4;

__device__ __forceinline__ unsigned short f2bf(float f) {
  unsigned u = __float_as_uint(f);
  unsigned r = (u + 0x7fffu + ((u >> 16) & 1u)) >> 16;
  return (unsigned short)r;
}
__device__ __forceinline__ unsigned pack_bf2(float lo, float hi) {
  return (unsigned)f2bf(lo) | ((unsigned)f2bf(hi) << 16);
}
__device__ __forceinline__ void gl_lds16(const void* g, void* l) {
  __builtin_amdgcn_global_load_lds(
      (const __attribute__((address_space(1))) unsigned int*)g,
      (__attribute__((address_space(3))) unsigned int*)l, 16, 0, 0);
}

// ---------------- BatchNorm stats ----------------
__global__ void k_colstats(const float* __restrict__ x, float* __restrict__ musum,
                           float* __restrict__ msqsum) {
  int c = threadIdx.x;            // 384
  int r0 = blockIdx.x * 128;      // 64 blocks
  float s = 0.f, s2 = 0.f;
  for (int r = 0; r < 128; ++r) {
    float v = x[(r0 + r) * DD + c];
    s += v; s2 += v * v;
  }
  atomicAdd(&musum[c], s);
  atomicAdd(&msqsum[c], s2);
}

__global__ void k_finstats(const float* __restrict__ musum, const float* __restrict__ msqsum,
                           float* __restrict__ mu, float* __restrict__ rstd) {
  int c = threadIdx.x;
  float m = musum[c] * (1.f / NN);
  float v = msqsum[c] * (1.f / NN) - m * m;
  mu[c] = m;
  rstd[c] = rsqrtf(v + 1e-5f);
}

// h = gamma*(x-mu)*rstd + beta ; ninv = 1/||h||_row ; h_bf = bf16(h)
__global__ void k_bn(const float* __restrict__ x, const float* __restrict__ gamma,
                     const float* __restrict__ beta, const float* __restrict__ mu,
                     const float* __restrict__ rstd, float* __restrict__ h,
                     short* __restrict__ h_bf, float* __restrict__ ninv) {
  int n = blockIdx.x;
  int t = threadIdx.x;  // 64
  float ss = 0.f;
#pragma unroll
  for (int i = 0; i < 6; ++i) {
    int c = t + i * 64;
    float v = gamma[c] * (x[n * DD + c] - mu[c]) * rstd[c] + beta[c];
    h[n * DD + c] = v;
    h_bf[n * DD + c] = (short)f2bf(v);
    ss += v * v;
  }
#pragma unroll
  for (int m = 32; m; m >>= 1) ss += __shfl_xor(ss, m, 64);
  if (t == 0) ninv[n] = rsqrtf(ss);
}

// ---------------- degree histograms ----------------
__global__ void k_counts(const int* __restrict__ ei, const int* __restrict__ et,
                         int* __restrict__ c_tot, int* __restrict__ c_rel) {
  int e = blockIdx.x * blockDim.x + threadIdx.x;
  if (e >= NE) return;
  int dst = ei[NE + e];
  int r = et[e];
  atomicAdd(&c_tot[dst], 1);
  atomicAdd(&c_rel[dst * NR + r], 1);
}

// exclusive scan of c_tot (8192) -> row_ptr[8193], cursor copy
__global__ void k_scan(const int* __restrict__ c_tot, int* __restrict__ row_ptr,
                       int* __restrict__ cursor) {
  __shared__ int part[1024];
  int t = threadIdx.x;
  int base = t * 8;
  int v[8]; int s = 0;
#pragma unroll
  for (int i = 0; i < 8; ++i) { v[i] = c_tot[base + i]; s += v[i]; }
  part[t] = s;
  __syncthreads();
  for (int off = 1; off < 1024; off <<= 1) {
    int add = (t >= off) ? part[t - off] : 0;
    __syncthreads();
    part[t] += add;
    __syncthreads();
  }
  int run = (t == 0) ? 0 : part[t - 1];
  if (t == 0) row_ptr[0] = 0;
#pragma unroll
  for (int i = 0; i < 8; ++i) {
    cursor[base + i] = run;
    run += v[i];
    row_ptr[base + i + 1] = run;
  }
}

// ---------------- edge cosine weights (bf16 gather) ----------------
__global__ void k_we(const short* __restrict__ hb, const float* __restrict__ ninv,
                     const int* __restrict__ ei, float* __restrict__ w_e) {
  int lane = threadIdx.x & 63;
  int wv = blockIdx.x * (blockDim.x >> 6) + (threadIdx.x >> 6);
  int nw = gridDim.x * (blockDim.x >> 6);
  for (int e = wv; e < NE; e += nw) {
    int s = ei[e], d = ei[NE + e];
    const unsigned* hs = (const unsigned*)(hb + (size_t)s * DD);
    const unsigned* hd = (const unsigned*)(hb + (size_t)d * DD);
    float acc = 0.f;
#pragma unroll
    for (int i = 0; i < 3; ++i) {
      unsigned ua = hs[i * 64 + lane], ub = hd[i * 64 + lane];
      float alo = __uint_as_float(ua << 16), ahi = __uint_as_float(ua & 0xffff0000u);
      float blo = __uint_as_float(ub << 16), bhi = __uint_as_float(ub & 0xffff0000u);
      acc += alo * blo + ahi * bhi;
    }
#pragma unroll
    for (int m = 32; m; m >>= 1) acc += __shfl_xor(acc, m, 64);
    if (lane == 0) w_e[e] = acc * ninv[s] * ninv[d];
  }
}

// ---------------- CSR fill ----------------
__global__ void k_fill(const int* __restrict__ ei, const int* __restrict__ et,
                       const float* __restrict__ w_e, int* __restrict__ cursor,
                       int* __restrict__ meta, float* __restrict__ wsort) {
  int e = blockIdx.x * blockDim.x + threadIdx.x;
  if (e >= NE) return;
  int src = ei[e], dst = ei[NE + e];
  int pos = atomicAdd(&cursor[dst], 1);
  meta[pos] = src | (et[e] << 13);
  wsort[pos] = w_e[e];
}

// ---------------- per-relation aggregation of h (bf16 in/out) ----------------
// Agg[n][r*384+d] = f_r * sum_{e->n, rel=r} w_e * h[src][d];  SC[n][r] = f_r * sum w_e
__global__ void k_aggrel(const short* __restrict__ hb, const int* __restrict__ row_ptr,
                         const int* __restrict__ meta, const float* __restrict__ wsort,
                         const int* __restrict__ c_rel, const float* __restrict__ nc,
                         short* __restrict__ Agg, float* __restrict__ SC, int layer) {
  int n = blockIdx.x;
  int t = threadIdx.x;  // 192: thread owns cols 2t, 2t+1
  float a00 = 0, a01 = 0, a10 = 0, a11 = 0, a20 = 0, a21 = 0, a30 = 0, a31 = 0;
  float s0 = 0, s1 = 0, s2 = 0, s3 = 0;
  int beg = row_ptr[n], end = row_ptr[n + 1];
  for (int e = beg; e < end; ++e) {
    int m = meta[e];
    float w = wsort[e];
    int src = m & 8191;
    int r = m >> 13;
    unsigned u = ((const unsigned*)(hb + (size_t)src * DD))[t];
    float lo = __uint_as_float(u << 16), hi = __uint_as_float(u & 0xffff0000u);
    if (r == 0)      { a00 += w * lo; a01 += w * hi; s0 += w; }
    else if (r == 1) { a10 += w * lo; a11 += w * hi; s1 += w; }
    else if (r == 2) { a20 += w * lo; a21 += w * hi; s2 += w; }
    else             { a30 += w * lo; a31 += w * hi; s3 += w; }
  }
  float f[4];
#pragma unroll
  for (int r = 0; r < 4; ++r) {
    int c = c_rel[n * 4 + r];
    f[r] = 1.f / (nc[layer * 4 + r] * (float)(c > 1 ? c : 1));
  }
  unsigned* an = (unsigned*)(Agg + (size_t)n * 1536);
  an[0 * 192 + t] = pack_bf2(a00 * f[0], a01 * f[0]);
  an[1 * 192 + t] = pack_bf2(a10 * f[1], a11 * f[1]);
  an[2 * 192 + t] = pack_bf2(a20 * f[2], a21 * f[2]);
  an[3 * 192 + t] = pack_bf2(a30 * f[3], a31 * f[3]);
  if (t == 0) {
    SC[n * 4 + 0] = s0 * f[0]; SC[n * 4 + 1] = s1 * f[1];
    SC[n * 4 + 2] = s2 * f[2]; SC[n * 4 + 3] = s3 * f[3];
  }
}

// ---------------- MP mean aggregation of rel_out (bf16) ----------------
// B1[n][0:384] = mean_{e->n} B1[src][384:768]
__global__ void k_aggmp(short* __restrict__ B1, const int* __restrict__ row_ptr,
                        const int* __restrict__ meta) {
  int n = blockIdx.x;
  int t = threadIdx.x;  // 192
  float ax = 0, ay = 0;
  int beg = row_ptr[n], end = row_ptr[n + 1];
  for (int e = beg; e < end; ++e) {
    int src = meta[e] & 8191;
    unsigned u = ((const unsigned*)(B1 + (size_t)src * 768 + 384))[t];
    ax += __uint_as_float(u << 16);
    ay += __uint_as_float(u & 0xffff0000u);
  }
  float inv = (end > beg) ? 1.f / (float)(end - beg) : 0.f;
  ((unsigned*)(B1 + (size_t)n * 768))[t] = pack_bf2(ax * inv, ay * inv);
}

// ---------------- weight packing (fp32 -> bf16) ----------------
__global__ void k_pack1(const float* __restrict__ W_rel, short* __restrict__ Wcat, int layer) {
  int idx = blockIdx.x * blockDim.x + threadIdx.x;  // 384*1536
  if (idx >= 384 * 1536) return;
  int i = idx / 1536, kk = idx - i * 1536;
  int r = kk / 384, k = kk - r * 384;
  Wcat[idx] = (short)f2bf(W_rel[(((size_t)(layer * NR + r) * DD) + i) * DD + k]);
}
__global__ void k_pack2(const float* __restrict__ W_msg, const float* __restrict__ W_self,
                        short* __restrict__ Wcat2, int layer) {
  int idx = blockIdx.x * blockDim.x + threadIdx.x;  // 384*768
  if (idx >= 384 * 768) return;
  int i = idx / 768, kk = idx - i * 768;
  float v = (kk < 384) ? W_msg[((size_t)layer * DD + i) * DD + kk]
                       : W_self[((size_t)layer * DD + i) * DD + kk - 384];
  Wcat2[idx] = (short)f2bf(v);
}

// ---------------- bf16 MFMA NT GEMM: C[8192 x 384] = A[8192 x K] * Bp[384 x K]^T --------
// m97 structure: 128x128 tile, 4 waves (each 64x64), BK=32, global_load_lds w=16.
// MODE 0: C = relu(acc + sum_r SC[row][r]*b_rel[r][col]) -> bf16 B1[:,384:768]
// MODE 1: h = relu(acc + deg?b_msg + b_self) + h  (fp32), also h_bf = bf16(h)
template <int MODE>
__global__ __launch_bounds__(256) void k_gemm_mfma(
    const short* __restrict__ A, int K, const short* __restrict__ Bp,
    const float* __restrict__ SC, const float* __restrict__ brel_l,
    const float* __restrict__ bmsg_l, const float* __restrict__ bself_l,
    const int* __restrict__ row_ptr, float* __restrict__ h,
    short* __restrict__ h_bf, short* __restrict__ Cout) {
  __shared__ short As[128 * 32];
  __shared__ short Bs[128 * 32];
  int tid = threadIdx.x;
  int lane = tid & 63;
  int w = tid >> 6;              // 0..3
  int wr = w >> 1, wc = w & 1;   // wave tile origin (wr*64, wc*64)
  int bm = blockIdx.x, bn = blockIdx.y;

  // staging: chunk ch covers tile row ch/4, k-octet ch%4 (16B each)
  int r0 = tid >> 2, c0 = (tid & 3) * 8;
  const short* Ag0 = A + (size_t)(bm * 128 + r0) * K + c0;
  const short* Ag1 = A + (size_t)(bm * 128 + r0 + 64) * K + c0;
  const short* Bg0 = Bp + (size_t)(bn * 128 + r0) * K + c0;
  const short* Bg1 = Bp + (size_t)(bn * 128 + r0 + 64) * K + c0;
  short* Asl0 = As + w * 512;          // wave-uniform LDS bases (lane*16B added by HW)
  short* Asl1 = As + 2048 + w * 512;
  short* Bsl0 = Bs + w * 512;
  short* Bsl1 = Bs + 2048 + w * 512;

  f32x4 acc[4][4] = {};
  int fr = lane & 15, fk = (lane >> 4) * 8;
  for (int k0 = 0; k0 < K; k0 += 32) {
    __syncthreads();  // previous iteration's LDS reads complete
    gl_lds16(Ag0 + k0, Asl0);
    gl_lds16(Ag1 + k0, Asl1);
    gl_lds16(Bg0 + k0, Bsl0);
    gl_lds16(Bg1 + k0, Bsl1);
    __syncthreads();  // staging drained (vmcnt(0) before barrier)
    bf16x8 a[4], b[4];
#pragma unroll
    for (int i = 0; i < 4; ++i)
      a[i] = *(const bf16x8*)&As[(wr * 64 + i * 16 + fr) * 32 + fk];
#pragma unroll
    for (int j = 0; j < 4; ++j)
      b[j] = *(const bf16x8*)&Bs[(wc * 64 + j * 16 + fr) * 32 + fk];
#pragma unroll
    for (int i = 0; i < 4; ++i)
#pragma unroll
      for (int j = 0; j < 4; ++j)
        acc[i][j] = __builtin_amdgcn_mfma_f32_16x16x32_bf16(a[i], b[j], acc[i][j], 0, 0, 0);
  }

  // epilogue: C/D layout col=lane&15, row=(lane>>4)*4+reg
  int cr = (lane >> 4) * 4;
  int cc = lane & 15;
#pragma unroll
  for (int i = 0; i < 4; ++i) {
#pragma unroll
    for (int jj = 0; jj < 4; ++jj) {
      int row = bm * 128 + wr * 64 + i * 16 + cr + jj;
      if (MODE == 0) {
        float4 sc = *(const float4*)&SC[row * 4];
#pragma unroll
        for (int j = 0; j < 4; ++j) {
          int col = bn * 128 + wc * 64 + j * 16 + cc;
          float v = acc[i][j][jj] + sc.x * brel_l[col] + sc.y * brel_l[384 + col] +
                    sc.z * brel_l[768 + col] + sc.w * brel_l[1152 + col];
          Cout[(size_t)row * 768 + 384 + col] = (short)f2bf(fmaxf(v, 0.f));
        }
      } else {
        float bmul = (row_ptr[row + 1] > row_ptr[row]) ? 1.f : 0.f;
#pragma unroll
        for (int j = 0; j < 4; ++j) {
          int col = bn * 128 + wc * 64 + j * 16 + cc;
          float v = acc[i][j][jj] + bmul * bmsg_l[col] + bself_l[col];
          float o = fmaxf(v, 0.f) + h[(size_t)row * DD + col];
          h[(size_t)row * DD + col] = o;
          h_bf[(size_t)row * DD + col] = (short)f2bf(o);
        }
      }
    }
  }
}

// ---------------- final per-batch mean ----------------
__global__ void k_out(const float* __restrict__ h, float* __restrict__ out) {
  int b = blockIdx.x;   // 64
  int c = threadIdx.x;  // 384
  float s = 0.f;
  for (int j = 0; j < 128; ++j) s += h[(size_t)(b * 128 + j) * DD + c];
  out[b * DD + c] = s * (1.f / 128.f);
}

extern "C" void kernel_launch(void* const* d_in, const int* in_sizes, int n_in,
                              void* d_out, int out_size, void* d_ws, size_t ws_size,
                              hipStream_t stream) {
  const float* x      = (const float*)d_in[0];
  const int*   ei     = (const int*)d_in[1];
  const int*   et     = (const int*)d_in[2];
  const float* gamma  = (const float*)d_in[3];
  const float* beta   = (const float*)d_in[4];
  const float* W_rel  = (const float*)d_in[5];
  const float* b_rel  = (const float*)d_in[6];
  const float* nc     = (const float*)d_in[7];
  const float* W_msg  = (const float*)d_in[8];
  const float* b_msg  = (const float*)d_in[9];
  const float* W_self = (const float*)d_in[10];
  const float* b_self = (const float*)d_in[11];
  float* out = (float*)d_out;

  char* ws = (char*)d_ws;
  size_t off = 0;
  auto alloc = [&](size_t bytes) -> void* {
    void* p = ws + off;
    off = (off + bytes + 255) & ~(size_t)255;
    return p;
  };
  float* h      = (float*)alloc((size_t)NN * DD * 4);
  short* h_bf   = (short*)alloc((size_t)NN * DD * 2);
  short* Agg    = (short*)alloc((size_t)NN * 1536 * 2);
  short* B1     = (short*)alloc((size_t)NN * 768 * 2);
  short* Wcat   = (short*)alloc((size_t)384 * 1536 * 2);
  short* Wcat2  = (short*)alloc((size_t)384 * 768 * 2);
  float* SC     = (float*)alloc((size_t)NN * 4 * 4);
  float* w_e    = (float*)alloc((size_t)NE * 4);
  int*   meta   = (int*)alloc((size_t)NE * 4);
  float* wsort  = (float*)alloc((size_t)NE * 4);
  int*   row_ptr= (int*)alloc((size_t)(NN + 1) * 4);
  int*   cursor = (int*)alloc((size_t)NN * 4);
  float* ninv   = (float*)alloc((size_t)NN * 4);
  char*  zb     = (char*)alloc(166912);  // musum|msqsum|c_tot|c_rel contiguous, zeroed
  float* musum  = (float*)(zb);
  float* msqsum = (float*)(zb + 1536);
  int*   c_tot  = (int*)(zb + 3072);
  int*   c_rel  = (int*)(zb + 35840);
  float* mu     = (float*)alloc(DD * 4);
  float* rstd   = (float*)alloc(DD * 4);

  hipMemsetAsync(zb, 0, 166912, stream);
  k_colstats<<<64, 384, 0, stream>>>(x, musum, msqsum);
  k_finstats<<<1, 384, 0, stream>>>(musum, msqsum, mu, rstd);
  k_bn<<<NN, 64, 0, stream>>>(x, gamma, beta, mu, rstd, h, h_bf, ninv);
  k_counts<<<NE / 256, 256, 0, stream>>>(ei, et, c_tot, c_rel);
  k_scan<<<1, 1024, 0, stream>>>(c_tot, row_ptr, cursor);
  k_we<<<2048, 256, 0, stream>>>(h_bf, ninv, ei, w_e);
  k_fill<<<NE / 256, 256, 0, stream>>>(ei, et, w_e, cursor, meta, wsort);

  for (int l = 0; l < NL; ++l) {
    k_pack1<<<(384 * 1536 + 255) / 256, 256, 0, stream>>>(W_rel, Wcat, l);
    k_pack2<<<(384 * 768 + 255) / 256, 256, 0, stream>>>(W_msg, W_self, Wcat2, l);
    k_aggrel<<<NN, 192, 0, stream>>>(h_bf, row_ptr, meta, wsort, c_rel, nc, Agg, SC, l);
    k_gemm_mfma<0><<<dim3(64, 3), 256, 0, stream>>>(Agg, 1536, Wcat, SC, b_rel + l * NR * DD,
                                                    nullptr, nullptr, nullptr, nullptr,
                                                    nullptr, B1);
    k_aggmp<<<NN, 192, 0, stream>>>(B1, row_ptr, meta);
    k_gemm_mfma<1><<<dim3(64, 3), 256, 0, stream>>>(B1, 768, Wcat2, nullptr, nullptr,
                                                    b_msg + l * DD, b_self + l * DD, row_ptr,
                                                    h, h_bf, nullptr);
  }
  k_out<<<64, 384, 0, stream>>>(h, out);
}

// Round 3
// 395.293 us; speedup vs baseline: 2.2227x; 1.3203x over previous
//
#include <hip/hip_runtime.h>
#include <hip/hip_bf16.h>

#define NN 8192
#define DD 384
#define NE 262144
#define NR 4
#define NL 2
#define NB 64

typedef __attribute__((ext_vector_type(8))) short bf16x8;
typedef __attribute__((ext_vector_type(4))) float f32x4;

__device__ __forceinline__ unsigned short f2bf(float f) {
  unsigned u = __float_as_uint(f);
  unsigned r = (u + 0x7fffu + ((u >> 16) & 1u)) >> 16;
  return (unsigned short)r;
}
__device__ __forceinline__ unsigned pack_bf2(float lo, float hi) {
  return (unsigned)f2bf(lo) | ((unsigned)f2bf(hi) << 16);
}
__device__ __forceinline__ float bflo(unsigned u) { return __uint_as_float(u << 16); }
__device__ __forceinline__ float bfhi(unsigned u) { return __uint_as_float(u & 0xffff0000u); }
__device__ __forceinline__ void gl_lds16(const void* g, void* l) {
  __builtin_amdgcn_global_load_lds(
      (const __attribute__((address_space(1))) unsigned int*)g,
      (__attribute__((address_space(3))) unsigned int*)l, 16, 0, 0);
}

// ---------------- BatchNorm stats ----------------
__global__ void k_colstats(const float* __restrict__ x, float* __restrict__ musum,
                           float* __restrict__ msqsum) {
  int c = threadIdx.x;            // 384
  int r0 = blockIdx.x * 128;      // 64 blocks
  float s = 0.f, s2 = 0.f;
  for (int r = 0; r < 128; ++r) {
    float v = x[(r0 + r) * DD + c];
    s += v; s2 += v * v;
  }
  atomicAdd(&musum[c], s);
  atomicAdd(&msqsum[c], s2);
}

__global__ void k_finstats(const float* __restrict__ musum, const float* __restrict__ msqsum,
                           float* __restrict__ mu, float* __restrict__ rstd) {
  int c = threadIdx.x;
  float m = musum[c] * (1.f / NN);
  float v = msqsum[c] * (1.f / NN) - m * m;
  mu[c] = m;
  rstd[c] = rsqrtf(v + 1e-5f);
}

// h = gamma*(x-mu)*rstd + beta ; ninv = 1/||h||_row ; h_bf = bf16(h)
__global__ void k_bn(const float* __restrict__ x, const float* __restrict__ gamma,
                     const float* __restrict__ beta, const float* __restrict__ mu,
                     const float* __restrict__ rstd, float* __restrict__ h,
                     short* __restrict__ h_bf, float* __restrict__ ninv) {
  int n = blockIdx.x;
  int t = threadIdx.x;  // 64
  float ss = 0.f;
#pragma unroll
  for (int i = 0; i < 6; ++i) {
    int c = t + i * 64;
    float v = gamma[c] * (x[n * DD + c] - mu[c]) * rstd[c] + beta[c];
    h[n * DD + c] = v;
    h_bf[n * DD + c] = (short)f2bf(v);
    ss += v * v;
  }
#pragma unroll
  for (int m = 32; m; m >>= 1) ss += __shfl_xor(ss, m, 64);
  if (t == 0) ninv[n] = rsqrtf(ss);
}

// ---------------- per-(dst,rel) histogram ----------------
__global__ void k_counts(const int* __restrict__ ei, const int* __restrict__ et,
                         int* __restrict__ c_rel) {
  int e = blockIdx.x * blockDim.x + threadIdx.x;
  if (e >= NE) return;
  int dst = ei[NE + e];
  atomicAdd(&c_rel[dst * NR + et[e]], 1);
}

// exclusive scan of c_rel (32768) -> rp2[32769], cursor copy
__global__ void k_scan(const int* __restrict__ c_rel, int* __restrict__ rp2,
                       int* __restrict__ cursor) {
  __shared__ int part[1024];
  int t = threadIdx.x;
  int base = t * 32;
  int v[32]; int s = 0;
#pragma unroll
  for (int i = 0; i < 32; ++i) { v[i] = c_rel[base + i]; s += v[i]; }
  part[t] = s;
  __syncthreads();
  for (int off = 1; off < 1024; off <<= 1) {
    int add = (t >= off) ? part[t - off] : 0;
    __syncthreads();
    part[t] += add;
    __syncthreads();
  }
  int run = (t == 0) ? 0 : part[t - 1];
  if (t == 0) rp2[0] = 0;
#pragma unroll
  for (int i = 0; i < 32; ++i) {
    cursor[base + i] = run;
    run += v[i];
    rp2[base + i + 1] = run;
  }
}

// ---------------- edge cosine weights (bf16 gather) ----------------
__global__ void k_we(const short* __restrict__ hb, const float* __restrict__ ninv,
                     const int* __restrict__ ei, float* __restrict__ w_e) {
  int lane = threadIdx.x & 63;
  int wv = blockIdx.x * (blockDim.x >> 6) + (threadIdx.x >> 6);
  int nw = gridDim.x * (blockDim.x >> 6);
  for (int e = wv; e < NE; e += nw) {
    int s = ei[e], d = ei[NE + e];
    const unsigned* hs = (const unsigned*)(hb + (size_t)s * DD);
    const unsigned* hd = (const unsigned*)(hb + (size_t)d * DD);
    float acc = 0.f;
#pragma unroll
    for (int i = 0; i < 3; ++i) {
      unsigned ua = hs[i * 64 + lane], ub = hd[i * 64 + lane];
      acc += bflo(ua) * bflo(ub) + bfhi(ua) * bfhi(ub);
    }
#pragma unroll
    for (int m = 32; m; m >>= 1) acc += __shfl_xor(acc, m, 64);
    if (lane == 0) w_e[e] = acc * ninv[s] * ninv[d];
  }
}

// ---------------- CSR fill (sorted by dst, then relation) ----------------
__global__ void k_fill(const int* __restrict__ ei, const int* __restrict__ et,
                       const float* __restrict__ w_e, int* __restrict__ cursor,
                       int* __restrict__ meta, float* __restrict__ wsort) {
  int e = blockIdx.x * blockDim.x + threadIdx.x;
  if (e >= NE) return;
  int src = ei[e], dst = ei[NE + e];
  int pos = atomicAdd(&cursor[dst * NR + et[e]], 1);
  meta[pos] = src;
  wsort[pos] = w_e[e];
}

// ---------------- per-relation aggregation of h (bf16 in/out) ----------------
// 384 threads: 4 groups of 96 (one per relation), branchless contiguous segment walk.
// Agg[n][r*384+d] = f_r * sum_{e in seg(n,r)} w_e * h[src][d];  SC[n][r] = f_r * sum w_e
__global__ void k_aggrel(const short* __restrict__ hb, const int* __restrict__ rp2,
                         const int* __restrict__ meta, const float* __restrict__ wsort,
                         const float* __restrict__ nc, short* __restrict__ Agg,
                         float* __restrict__ SC, int layer) {
  int n = blockIdx.x;
  int t = threadIdx.x;       // 384
  int r = t / 96;            // relation group
  int i = t - r * 96;        // 0..95, owns cols [4i, 4i+4)
  int beg = rp2[n * 4 + r], end = rp2[n * 4 + r + 1];
  float a0 = 0, a1 = 0, a2 = 0, a3 = 0, s = 0;
  int e = beg;
  for (; e + 1 < end; e += 2) {
    int s0 = meta[e], s1 = meta[e + 1];
    float w0 = wsort[e], w1 = wsort[e + 1];
    uint2 u0 = ((const uint2*)(hb + (size_t)s0 * DD))[i];
    uint2 u1 = ((const uint2*)(hb + (size_t)s1 * DD))[i];
    a0 += w0 * bflo(u0.x); a1 += w0 * bfhi(u0.x);
    a2 += w0 * bflo(u0.y); a3 += w0 * bfhi(u0.y);
    a0 += w1 * bflo(u1.x); a1 += w1 * bfhi(u1.x);
    a2 += w1 * bflo(u1.y); a3 += w1 * bfhi(u1.y);
    s += w0 + w1;
  }
  if (e < end) {
    int s0 = meta[e];
    float w0 = wsort[e];
    uint2 u0 = ((const uint2*)(hb + (size_t)s0 * DD))[i];
    a0 += w0 * bflo(u0.x); a1 += w0 * bfhi(u0.x);
    a2 += w0 * bflo(u0.y); a3 += w0 * bfhi(u0.y);
    s += w0;
  }
  int c = end - beg;
  float f = 1.f / (nc[layer * 4 + r] * (float)(c > 1 ? c : 1));
  uint2 o;
  o.x = pack_bf2(a0 * f, a1 * f);
  o.y = pack_bf2(a2 * f, a3 * f);
  ((uint2*)(Agg + (size_t)n * 1536 + r * 384))[i] = o;
  if (i == 0) SC[n * 4 + r] = s * f;
}

// ---------------- MP mean aggregation of rel_out (bf16) ----------------
// B1[n][0:384] = mean_{e->n} B1[src][384:768]; 4 groups of 96 split edges mod 4.
__global__ void k_aggmp(short* __restrict__ B1, const int* __restrict__ rp2,
                        const int* __restrict__ meta) {
  __shared__ float red[3][96][4];
  int n = blockIdx.x;
  int t = threadIdx.x;  // 384
  int g = t / 96, i = t - g * 96;
  int beg = rp2[n * 4], end = rp2[n * 4 + 4];
  float a0 = 0, a1 = 0, a2 = 0, a3 = 0;
  for (int e = beg + g; e < end; e += 4) {
    int src = meta[e];
    uint2 u = ((const uint2*)(B1 + (size_t)src * 768 + 384))[i];
    a0 += bflo(u.x); a1 += bfhi(u.x);
    a2 += bflo(u.y); a3 += bfhi(u.y);
  }
  if (g) {
    red[g - 1][i][0] = a0; red[g - 1][i][1] = a1;
    red[g - 1][i][2] = a2; red[g - 1][i][3] = a3;
  }
  __syncthreads();
  if (g == 0) {
#pragma unroll
    for (int k = 0; k < 3; ++k) {
      a0 += red[k][i][0]; a1 += red[k][i][1];
      a2 += red[k][i][2]; a3 += red[k][i][3];
    }
    float inv = (end > beg) ? 1.f / (float)(end - beg) : 0.f;
    uint2 o;
    o.x = pack_bf2(a0 * inv, a1 * inv);
    o.y = pack_bf2(a2 * inv, a3 * inv);
    ((uint2*)(B1 + (size_t)n * 768))[i] = o;
  }
}

// ---------------- weight packing (fp32 -> bf16) ----------------
__global__ void k_pack1(const float* __restrict__ W_rel, short* __restrict__ Wcat, int layer) {
  int idx = blockIdx.x * blockDim.x + threadIdx.x;  // 384*1536
  if (idx >= 384 * 1536) return;
  int i = idx / 1536, kk = idx - i * 1536;
  int r = kk / 384, k = kk - r * 384;
  Wcat[idx] = (short)f2bf(W_rel[(((size_t)(layer * NR + r) * DD) + i) * DD + k]);
}
__global__ void k_pack2(const float* __restrict__ W_msg, const float* __restrict__ W_self,
                        short* __restrict__ Wcat2, int layer) {
  int idx = blockIdx.x * blockDim.x + threadIdx.x;  // 384*768
  if (idx >= 384 * 768) return;
  int i = idx / 768, kk = idx - i * 768;
  float v = (kk < 384) ? W_msg[((size_t)layer * DD + i) * DD + kk]
                       : W_self[((size_t)layer * DD + i) * DD + kk - 384];
  Wcat2[idx] = (short)f2bf(v);
}

// ---------------- bf16 MFMA NT GEMM: C[8192 x 384] = A[8192 x K] * Bp[384 x K]^T --------
// 64x64 tile, 4 waves (each 32x32), BK=32, global_load_lds w=16. Grid (128,6)=768 blocks.
// MODE 0: C = relu(acc + sum_r SC[row][r]*b_rel[r][col]) -> bf16 B1[:,384:768]
// MODE 1: h = relu(acc + deg?b_msg + b_self) + h  (fp32), also h_bf = bf16(h)
template <int MODE>
__global__ __launch_bounds__(256) void k_gemm_mfma(
    const short* __restrict__ A, int K, const short* __restrict__ Bp,
    const float* __restrict__ SC, const float* __restrict__ brel_l,
    const float* __restrict__ bmsg_l, const float* __restrict__ bself_l,
    const int* __restrict__ rp2, float* __restrict__ h,
    short* __restrict__ h_bf, short* __restrict__ Cout) {
  __shared__ short As[64 * 32];
  __shared__ short Bs[64 * 32];
  int tid = threadIdx.x;
  int lane = tid & 63;
  int w = tid >> 6;              // 0..3
  int wr = w >> 1, wc = w & 1;   // wave tile origin (wr*32, wc*32)
  int bm = blockIdx.x, bn = blockIdx.y;

  // staging: chunk tid covers tile row tid/4, k-octet tid%4 (16B each)
  const short* Ag = A + (size_t)(bm * 64 + (tid >> 2)) * K + (tid & 3) * 8;
  const short* Bg = Bp + (size_t)(bn * 64 + (tid >> 2)) * K + (tid & 3) * 8;
  short* Asl = As + w * 512;  // wave-uniform LDS base (lane*16B added by HW)
  short* Bsl = Bs + w * 512;

  f32x4 acc[2][2] = {};
  int fr = lane & 15, fk = (lane >> 4) * 8;
  for (int k0 = 0; k0 < K; k0 += 32) {
    __syncthreads();  // previous iteration's LDS reads complete
    gl_lds16(Ag + k0, Asl);
    gl_lds16(Bg + k0, Bsl);
    __syncthreads();  // staging drained (vmcnt(0) before barrier)
    bf16x8 a[2], b[2];
#pragma unroll
    for (int i = 0; i < 2; ++i)
      a[i] = *(const bf16x8*)&As[(wr * 32 + i * 16 + fr) * 32 + fk];
#pragma unroll
    for (int j = 0; j < 2; ++j)
      b[j] = *(const bf16x8*)&Bs[(wc * 32 + j * 16 + fr) * 32 + fk];
#pragma unroll
    for (int i = 0; i < 2; ++i)
#pragma unroll
      for (int j = 0; j < 2; ++j)
        acc[i][j] = __builtin_amdgcn_mfma_f32_16x16x32_bf16(a[i], b[j], acc[i][j], 0, 0, 0);
  }

  // epilogue: C/D layout col=lane&15, row=(lane>>4)*4+reg
  int cr = (lane >> 4) * 4;
  int cc = lane & 15;
#pragma unroll
  for (int i = 0; i < 2; ++i) {
#pragma unroll
    for (int jj = 0; jj < 4; ++jj) {
      int row = bm * 64 + wr * 32 + i * 16 + cr + jj;
      if (MODE == 0) {
        float4 sc = *(const float4*)&SC[row * 4];
#pragma unroll
        for (int j = 0; j < 2; ++j) {
          int col = bn * 64 + wc * 32 + j * 16 + cc;
          float v = acc[i][j][jj] + sc.x * brel_l[col] + sc.y * brel_l[384 + col] +
                    sc.z * brel_l[768 + col] + sc.w * brel_l[1152 + col];
          Cout[(size_t)row * 768 + 384 + col] = (short)f2bf(fmaxf(v, 0.f));
        }
      } else {
        float bmul = (rp2[(row + 1) * 4] > rp2[row * 4]) ? 1.f : 0.f;
#pragma unroll
        for (int j = 0; j < 2; ++j) {
          int col = bn * 64 + wc * 32 + j * 16 + cc;
          float v = acc[i][j][jj] + bmul * bmsg_l[col] + bself_l[col];
          float o = fmaxf(v, 0.f) + h[(size_t)row * DD + col];
          h[(size_t)row * DD + col] = o;
          h_bf[(size_t)row * DD + col] = (short)f2bf(o);
        }
      }
    }
  }
}

// ---------------- final per-batch mean ----------------
__global__ void k_out(const float* __restrict__ h, float* __restrict__ out) {
  int b = blockIdx.x;   // 64
  int c = threadIdx.x;  // 384
  float s = 0.f;
  for (int j = 0; j < 128; ++j) s += h[(size_t)(b * 128 + j) * DD + c];
  out[b * DD + c] = s * (1.f / 128.f);
}

extern "C" void kernel_launch(void* const* d_in, const int* in_sizes, int n_in,
                              void* d_out, int out_size, void* d_ws, size_t ws_size,
                              hipStream_t stream) {
  const float* x      = (const float*)d_in[0];
  const int*   ei     = (const int*)d_in[1];
  const int*   et     = (const int*)d_in[2];
  const float* gamma  = (const float*)d_in[3];
  const float* beta   = (const float*)d_in[4];
  const float* W_rel  = (const float*)d_in[5];
  const float* b_rel  = (const float*)d_in[6];
  const float* nc     = (const float*)d_in[7];
  const float* W_msg  = (const float*)d_in[8];
  const float* b_msg  = (const float*)d_in[9];
  const float* W_self = (const float*)d_in[10];
  const float* b_self = (const float*)d_in[11];
  float* out = (float*)d_out;

  char* ws = (char*)d_ws;
  size_t off = 0;
  auto alloc = [&](size_t bytes) -> void* {
    void* p = ws + off;
    off = (off + bytes + 255) & ~(size_t)255;
    return p;
  };
  float* h      = (float*)alloc((size_t)NN * DD * 4);
  short* h_bf   = (short*)alloc((size_t)NN * DD * 2);
  short* Agg    = (short*)alloc((size_t)NN * 1536 * 2);
  short* B1     = (short*)alloc((size_t)NN * 768 * 2);
  short* Wcat   = (short*)alloc((size_t)384 * 1536 * 2);
  short* Wcat2  = (short*)alloc((size_t)384 * 768 * 2);
  float* SC     = (float*)alloc((size_t)NN * 4 * 4);
  float* w_e    = (float*)alloc((size_t)NE * 4);
  int*   meta   = (int*)alloc((size_t)NE * 4);
  float* wsort  = (float*)alloc((size_t)NE * 4);
  int*   rp2    = (int*)alloc((size_t)(NN * 4 + 1) * 4);
  int*   cursor = (int*)alloc((size_t)NN * 4 * 4);
  float* ninv   = (float*)alloc((size_t)NN * 4);
  char*  zb     = (char*)alloc(134144);  // musum|msqsum|c_rel contiguous, zeroed
  float* musum  = (float*)(zb);
  float* msqsum = (float*)(zb + 1536);
  int*   c_rel  = (int*)(zb + 3072);
  float* mu     = (float*)alloc(DD * 4);
  float* rstd   = (float*)alloc(DD * 4);

  hipMemsetAsync(zb, 0, 134144, stream);
  k_colstats<<<64, 384, 0, stream>>>(x, musum, msqsum);
  k_finstats<<<1, 384, 0, stream>>>(musum, msqsum, mu, rstd);
  k_bn<<<NN, 64, 0, stream>>>(x, gamma, beta, mu, rstd, h, h_bf, ninv);
  k_counts<<<NE / 256, 256, 0, stream>>>(ei, et, c_rel);
  k_scan<<<1, 1024, 0, stream>>>(c_rel, rp2, cursor);
  k_we<<<2048, 256, 0, stream>>>(h_bf, ninv, ei, w_e);
  k_fill<<<NE / 256, 256, 0, stream>>>(ei, et, w_e, cursor, meta, wsort);

  for (int l = 0; l < NL; ++l) {
    k_pack1<<<(384 * 1536 + 255) / 256, 256, 0, stream>>>(W_rel, Wcat, l);
    k_pack2<<<(384 * 768 + 255) / 256, 256, 0, stream>>>(W_msg, W_self, Wcat2, l);
    k_aggrel<<<NN, 384, 0, stream>>>(h_bf, rp2, meta, wsort, nc, Agg, SC, l);
    k_gemm_mfma<0><<<dim3(128, 6), 256, 0, stream>>>(Agg, 1536, Wcat, SC, b_rel + l * NR * DD,
                                                     nullptr, nullptr, nullptr, nullptr,
                                                     nullptr, B1);
    k_aggmp<<<NN, 384, 0, stream>>>(B1, rp2, meta);
    k_gemm_mfma<1><<<dim3(128, 6), 256, 0, stream>>>(B1, 768, Wcat2, nullptr, nullptr,
                                                     b_msg + l * DD, b_self + l * DD, rp2,
                                                     h, h_bf, nullptr);
  }
  k_out<<<64, 384, 0, stream>>>(h, out);
}

// Round 5
// 328.713 us; speedup vs baseline: 2.6729x; 1.2025x over previous
//
#include <hip/hip_runtime.h>
#include <hip/hip_bf16.h>

#define NN 8192
#define DD 384
#define NE 262144
#define NR 4
#define NL 2
#define NB 64

typedef __attribute__((ext_vector_type(8))) short bf16x8;
typedef __attribute__((ext_vector_type(4))) float f32x4;

__device__ __forceinline__ unsigned short f2bf(float f) {
  unsigned u = __float_as_uint(f);
  unsigned r = (u + 0x7fffu + ((u >> 16) & 1u)) >> 16;
  return (unsigned short)r;
}
__device__ __forceinline__ unsigned pack_bf2(float lo, float hi) {
  return (unsigned)f2bf(lo) | ((unsigned)f2bf(hi) << 16);
}
__device__ __forceinline__ float bflo(unsigned u) { return __uint_as_float(u << 16); }
__device__ __forceinline__ float bfhi(unsigned u) { return __uint_as_float(u & 0xffff0000u); }
__device__ __forceinline__ void gl_lds16(const void* g, void* l) {
  __builtin_amdgcn_global_load_lds(
      (const __attribute__((address_space(1))) unsigned int*)g,
      (__attribute__((address_space(3))) unsigned int*)l, 16, 0, 0);
}
__device__ __forceinline__ float dot8(uint4 a, uint4 b) {
  return bflo(a.x) * bflo(b.x) + bfhi(a.x) * bfhi(b.x) +
         bflo(a.y) * bflo(b.y) + bfhi(a.y) * bfhi(b.y) +
         bflo(a.z) * bflo(b.z) + bfhi(a.z) * bfhi(b.z) +
         bflo(a.w) * bflo(b.w) + bfhi(a.w) * bfhi(b.w);
}

// ---------------- BatchNorm column sums (256 blocks x 32 rows) ----------------
__global__ void k_colstats(const float* __restrict__ x, float* __restrict__ musum,
                           float* __restrict__ msqsum) {
  int c = threadIdx.x;            // 384
  int r0 = blockIdx.x * 32;       // 256 blocks
  float s = 0.f, s2 = 0.f;
  for (int r = 0; r < 32; ++r) {
    float v = x[(size_t)(r0 + r) * DD + c];
    s += v; s2 += v * v;
  }
  atomicAdd(&musum[c], s);
  atomicAdd(&msqsum[c], s2);
}

// h = gamma*(x-mu)*rstd + beta ; ninv = 1/||h||_row ; h_bf = bf16(h)
__global__ void k_bn(const float* __restrict__ x, const float* __restrict__ gamma,
                     const float* __restrict__ beta, const float* __restrict__ musum,
                     const float* __restrict__ msqsum, float* __restrict__ h,
                     short* __restrict__ h_bf, float* __restrict__ ninv) {
  int n = blockIdx.x;
  int t = threadIdx.x;  // 64
  float ss = 0.f;
#pragma unroll
  for (int i = 0; i < 6; ++i) {
    int c = t + i * 64;
    float m = musum[c] * (1.f / NN);
    float var = msqsum[c] * (1.f / NN) - m * m;
    float v = gamma[c] * (x[(size_t)n * DD + c] - m) * rsqrtf(var + 1e-5f) + beta[c];
    h[(size_t)n * DD + c] = v;
    h_bf[(size_t)n * DD + c] = (short)f2bf(v);
    ss += v * v;
  }
#pragma unroll
  for (int m = 32; m; m >>= 1) ss += __shfl_xor(ss, m, 64);
  if (t == 0) ninv[n] = rsqrtf(ss);
}

// ---------------- per-(dst,rel) histogram ----------------
__global__ void k_counts(const int* __restrict__ ei, const int* __restrict__ et,
                         int* __restrict__ c_rel) {
  int e = blockIdx.x * blockDim.x + threadIdx.x;
  if (e >= NE) return;
  int dst = ei[NE + e];
  atomicAdd(&c_rel[dst * NR + et[e]], 1);
}

// exclusive scan of c_rel (32768) -> rp2[32769], cursor copy
__global__ void k_scan(const int* __restrict__ c_rel, int* __restrict__ rp2,
                       int* __restrict__ cursor) {
  __shared__ int part[1024];
  int t = threadIdx.x;
  int base = t * 32;
  int v[32]; int s = 0;
#pragma unroll
  for (int i = 0; i < 32; ++i) { v[i] = c_rel[base + i]; s += v[i]; }
  part[t] = s;
  __syncthreads();
  for (int off = 1; off < 1024; off <<= 1) {
    int add = (t >= off) ? part[t - off] : 0;
    __syncthreads();
    part[t] += add;
    __syncthreads();
  }
  int run = (t == 0) ? 0 : part[t - 1];
  if (t == 0) rp2[0] = 0;
#pragma unroll
  for (int i = 0; i < 32; ++i) {
    cursor[base + i] = run;
    run += v[i];
    rp2[base + i + 1] = run;
  }
}

// ---------------- edge cosine weights: 16-lane group per edge, 4 edges/wave --------
// row = 384 bf16 = 48 uint4; each lane loads 3 uint4 (sl, 16+sl, 32+sl).
__global__ void k_we(const short* __restrict__ hb, const float* __restrict__ ninv,
                     const int* __restrict__ ei, float* __restrict__ w_e) {
  int sl = threadIdx.x & 15;
  int grp = (blockIdx.x * blockDim.x + threadIdx.x) >> 4;
  int ngrp = (gridDim.x * blockDim.x) >> 4;
  for (int e = grp; e < NE; e += ngrp) {
    int s = ei[e], d = ei[NE + e];
    const uint4* hs = (const uint4*)(hb + (size_t)s * DD);
    const uint4* hd = (const uint4*)(hb + (size_t)d * DD);
    uint4 a0 = hs[sl], a1 = hs[16 + sl], a2 = hs[32 + sl];
    uint4 b0 = hd[sl], b1 = hd[16 + sl], b2 = hd[32 + sl];
    float acc = dot8(a0, b0) + dot8(a1, b1) + dot8(a2, b2);
#pragma unroll
    for (int m = 8; m; m >>= 1) acc += __shfl_xor(acc, m, 64);
    if (sl == 0) w_e[e] = acc * ninv[s] * ninv[d];
  }
}

// ---------------- CSR fill (sorted by dst, then relation) ----------------
__global__ void k_fill(const int* __restrict__ ei, const int* __restrict__ et,
                       const float* __restrict__ w_e, int* __restrict__ cursor,
                       int* __restrict__ meta, float* __restrict__ wsort) {
  int e = blockIdx.x * blockDim.x + threadIdx.x;
  if (e >= NE) return;
  int src = ei[e], dst = ei[NE + e];
  int pos = atomicAdd(&cursor[dst * NR + et[e]], 1);
  meta[pos] = src;
  wsort[pos] = w_e[e];
}

// ---------------- per-relation aggregation of h (bf16 in/out), 4-deep unroll ------
__global__ void k_aggrel(const short* __restrict__ hb, const int* __restrict__ rp2,
                         const int* __restrict__ meta, const float* __restrict__ wsort,
                         const float* __restrict__ nc, short* __restrict__ Agg,
                         float* __restrict__ SC, int layer) {
  int n = blockIdx.x;
  int t = threadIdx.x;       // 384
  int r = t / 96;            // relation group
  int i = t - r * 96;        // 0..95, owns cols [4i, 4i+4)
  int beg = rp2[n * 4 + r], end = rp2[n * 4 + r + 1];
  float a0 = 0, a1 = 0, a2 = 0, a3 = 0, s = 0;
  int e = beg;
  for (; e + 3 < end; e += 4) {
    int s0 = meta[e], s1 = meta[e + 1], s2 = meta[e + 2], s3 = meta[e + 3];
    float w0 = wsort[e], w1 = wsort[e + 1], w2 = wsort[e + 2], w3 = wsort[e + 3];
    uint2 u0 = ((const uint2*)(hb + (size_t)s0 * DD))[i];
    uint2 u1 = ((const uint2*)(hb + (size_t)s1 * DD))[i];
    uint2 u2 = ((const uint2*)(hb + (size_t)s2 * DD))[i];
    uint2 u3 = ((const uint2*)(hb + (size_t)s3 * DD))[i];
    a0 += w0 * bflo(u0.x) + w1 * bflo(u1.x) + w2 * bflo(u2.x) + w3 * bflo(u3.x);
    a1 += w0 * bfhi(u0.x) + w1 * bfhi(u1.x) + w2 * bfhi(u2.x) + w3 * bfhi(u3.x);
    a2 += w0 * bflo(u0.y) + w1 * bflo(u1.y) + w2 * bflo(u2.y) + w3 * bflo(u3.y);
    a3 += w0 * bfhi(u0.y) + w1 * bfhi(u1.y) + w2 * bfhi(u2.y) + w3 * bfhi(u3.y);
    s += w0 + w1 + w2 + w3;
  }
  for (; e < end; ++e) {
    int s0 = meta[e];
    float w0 = wsort[e];
    uint2 u0 = ((const uint2*)(hb + (size_t)s0 * DD))[i];
    a0 += w0 * bflo(u0.x); a1 += w0 * bfhi(u0.x);
    a2 += w0 * bflo(u0.y); a3 += w0 * bfhi(u0.y);
    s += w0;
  }
  int c = end - beg;
  float f = 1.f / (nc[layer * 4 + r] * (float)(c > 1 ? c : 1));
  uint2 o;
  o.x = pack_bf2(a0 * f, a1 * f);
  o.y = pack_bf2(a2 * f, a3 * f);
  ((uint2*)(Agg + (size_t)n * 1536 + r * 384))[i] = o;
  if (i == 0) SC[n * 4 + r] = s * f;
}

// ---------------- MP mean aggregation of rel_out (bf16), 4-deep unroll ------------
__global__ void k_aggmp(short* __restrict__ B1, const int* __restrict__ rp2,
                        const int* __restrict__ meta) {
  __shared__ float red[3][96][4];
  int n = blockIdx.x;
  int t = threadIdx.x;  // 384
  int g = t / 96, i = t - g * 96;
  int beg = rp2[n * 4], end = rp2[n * 4 + 4];
  float a0 = 0, a1 = 0, a2 = 0, a3 = 0;
  int e = beg + g;
  for (; e + 12 < end; e += 16) {
    int s0 = meta[e], s1 = meta[e + 4], s2 = meta[e + 8], s3 = meta[e + 12];
    uint2 u0 = ((const uint2*)(B1 + (size_t)s0 * 768 + 384))[i];
    uint2 u1 = ((const uint2*)(B1 + (size_t)s1 * 768 + 384))[i];
    uint2 u2 = ((const uint2*)(B1 + (size_t)s2 * 768 + 384))[i];
    uint2 u3 = ((const uint2*)(B1 + (size_t)s3 * 768 + 384))[i];
    a0 += bflo(u0.x) + bflo(u1.x) + bflo(u2.x) + bflo(u3.x);
    a1 += bfhi(u0.x) + bfhi(u1.x) + bfhi(u2.x) + bfhi(u3.x);
    a2 += bflo(u0.y) + bflo(u1.y) + bflo(u2.y) + bflo(u3.y);
    a3 += bfhi(u0.y) + bfhi(u1.y) + bfhi(u2.y) + bfhi(u3.y);
  }
  for (; e < end; e += 4) {
    int s0 = meta[e];
    uint2 u = ((const uint2*)(B1 + (size_t)s0 * 768 + 384))[i];
    a0 += bflo(u.x); a1 += bfhi(u.x);
    a2 += bflo(u.y); a3 += bfhi(u.y);
  }
  if (g) {
    red[g - 1][i][0] = a0; red[g - 1][i][1] = a1;
    red[g - 1][i][2] = a2; red[g - 1][i][3] = a3;
  }
  __syncthreads();
  if (g == 0) {
#pragma unroll
    for (int k = 0; k < 3; ++k) {
      a0 += red[k][i][0]; a1 += red[k][i][1];
      a2 += red[k][i][2]; a3 += red[k][i][3];
    }
    float inv = (end > beg) ? 1.f / (float)(end - beg) : 0.f;
    uint2 o;
    o.x = pack_bf2(a0 * inv, a1 * inv);
    o.y = pack_bf2(a2 * inv, a3 * inv);
    ((uint2*)(B1 + (size_t)n * 768))[i] = o;
  }
}

// ---------------- weight packing, both layers in one dispatch ----------------
// Wcat: [NL][384][1536] (rel r k-block), Wcat2: [NL][384][768] ([W_msg|W_self])
__global__ void k_packall(const float* __restrict__ W_rel, const float* __restrict__ W_msg,
                          const float* __restrict__ W_self, short* __restrict__ Wcat,
                          short* __restrict__ Wcat2) {
  const int T1 = NL * 384 * 1536;
  const int T2 = NL * 384 * 768;
  int idx = blockIdx.x * blockDim.x + threadIdx.x;
  if (idx < T1) {
    int l = idx / (384 * 1536);
    int rem = idx - l * 384 * 1536;
    int i = rem / 1536, kk = rem - i * 1536;
    int r = kk / 384, k = kk - r * 384;
    Wcat[idx] = (short)f2bf(W_rel[(((size_t)(l * NR + r) * DD) + i) * DD + k]);
  } else if (idx < T1 + T2) {
    int j = idx - T1;
    int l = j / (384 * 768);
    int rem = j - l * 384 * 768;
    int i = rem / 768, kk = rem - i * 768;
    float v = (kk < 384) ? W_msg[((size_t)l * DD + i) * DD + kk]
                         : W_self[((size_t)l * DD + i) * DD + kk - 384];
    Wcat2[j] = (short)f2bf(v);
  }
}

// ---------------- bf16 MFMA NT GEMM: C[8192 x 384] = A[8192 x K] * Bp[384 x K]^T --------
// 64x64 tile, 4 waves (each 32x32), BK=32, global_load_lds w=16. Grid (128,6)=768 blocks.
// MODE 0: C = relu(acc + sum_r SC[row][r]*b_rel[r][col]) -> bf16 B1[:,384:768]
// MODE 1: h = relu(acc + deg?b_msg + b_self) + h  (fp32), also h_bf = bf16(h)
template <int MODE>
__global__ __launch_bounds__(256) void k_gemm_mfma(
    const short* __restrict__ A, int K, const short* __restrict__ Bp,
    const float* __restrict__ SC, const float* __restrict__ brel_l,
    const float* __restrict__ bmsg_l, const float* __restrict__ bself_l,
    const int* __restrict__ rp2, float* __restrict__ h,
    short* __restrict__ h_bf, short* __restrict__ Cout) {
  __shared__ short As[64 * 32];
  __shared__ short Bs[64 * 32];
  int tid = threadIdx.x;
  int lane = tid & 63;
  int w = tid >> 6;              // 0..3
  int wr = w >> 1, wc = w & 1;   // wave tile origin (wr*32, wc*32)
  int bm = blockIdx.x, bn = blockIdx.y;

  const short* Ag = A + (size_t)(bm * 64 + (tid >> 2)) * K + (tid & 3) * 8;
  const short* Bg = Bp + (size_t)(bn * 64 + (tid >> 2)) * K + (tid & 3) * 8;
  short* Asl = As + w * 512;  // wave-uniform LDS base (lane*16B added by HW)
  short* Bsl = Bs + w * 512;

  f32x4 acc[2][2] = {};
  int fr = lane & 15, fk = (lane >> 4) * 8;
  for (int k0 = 0; k0 < K; k0 += 32) {
    __syncthreads();
    gl_lds16(Ag + k0, Asl);
    gl_lds16(Bg + k0, Bsl);
    __syncthreads();
    bf16x8 a[2], b[2];
#pragma unroll
    for (int i = 0; i < 2; ++i)
      a[i] = *(const bf16x8*)&As[(wr * 32 + i * 16 + fr) * 32 + fk];
#pragma unroll
    for (int j = 0; j < 2; ++j)
      b[j] = *(const bf16x8*)&Bs[(wc * 32 + j * 16 + fr) * 32 + fk];
#pragma unroll
    for (int i = 0; i < 2; ++i)
#pragma unroll
      for (int j = 0; j < 2; ++j)
        acc[i][j] = __builtin_amdgcn_mfma_f32_16x16x32_bf16(a[i], b[j], acc[i][j], 0, 0, 0);
  }

  int cr = (lane >> 4) * 4;
  int cc = lane & 15;
#pragma unroll
  for (int i = 0; i < 2; ++i) {
#pragma unroll
    for (int jj = 0; jj < 4; ++jj) {
      int row = bm * 64 + wr * 32 + i * 16 + cr + jj;
      if (MODE == 0) {
        float4 sc = *(const float4*)&SC[row * 4];
#pragma unroll
        for (int j = 0; j < 2; ++j) {
          int col = bn * 64 + wc * 32 + j * 16 + cc;
          float v = acc[i][j][jj] + sc.x * brel_l[col] + sc.y * brel_l[384 + col] +
                    sc.z * brel_l[768 + col] + sc.w * brel_l[1152 + col];
          Cout[(size_t)row * 768 + 384 + col] = (short)f2bf(fmaxf(v, 0.f));
        }
      } else {
        float bmul = (rp2[(row + 1) * 4] > rp2[row * 4]) ? 1.f : 0.f;
#pragma unroll
        for (int j = 0; j < 2; ++j) {
          int col = bn * 64 + wc * 32 + j * 16 + cc;
          float v = acc[i][j][jj] + bmul * bmsg_l[col] + bself_l[col];
          float o = fmaxf(v, 0.f) + h[(size_t)row * DD + col];
          h[(size_t)row * DD + col] = o;
          h_bf[(size_t)row * DD + col] = (short)f2bf(o);
        }
      }
    }
  }
}

// ---------------- final per-batch mean ----------------
__global__ void k_out(const float* __restrict__ h, float* __restrict__ out) {
  int b = blockIdx.x;   // 64
  int c = threadIdx.x;  // 384
  float s = 0.f;
  for (int j = 0; j < 128; ++j) s += h[(size_t)(b * 128 + j) * DD + c];
  out[b * DD + c] = s * (1.f / 128.f);
}

extern "C" void kernel_launch(void* const* d_in, const int* in_sizes, int n_in,
                              void* d_out, int out_size, void* d_ws, size_t ws_size,
                              hipStream_t stream) {
  const float* x      = (const float*)d_in[0];
  const int*   ei     = (const int*)d_in[1];
  const int*   et     = (const int*)d_in[2];
  const float* gamma  = (const float*)d_in[3];
  const float* beta   = (const float*)d_in[4];
  const float* W_rel  = (const float*)d_in[5];
  const float* b_rel  = (const float*)d_in[6];
  const float* nc     = (const float*)d_in[7];
  const float* W_msg  = (const float*)d_in[8];
  const float* b_msg  = (const float*)d_in[9];
  const float* W_self = (const float*)d_in[10];
  const float* b_self = (const float*)d_in[11];
  float* out = (float*)d_out;

  char* ws = (char*)d_ws;
  size_t off = 0;
  auto alloc = [&](size_t bytes) -> void* {
    void* p = ws + off;
    off = (off + bytes + 255) & ~(size_t)255;
    return p;
  };
  float* h      = (float*)alloc((size_t)NN * DD * 4);
  short* h_bf   = (short*)alloc((size_t)NN * DD * 2);
  short* Agg    = (short*)alloc((size_t)NN * 1536 * 2);
  short* B1     = (short*)alloc((size_t)NN * 768 * 2);
  short* Wcat   = (short*)alloc((size_t)NL * 384 * 1536 * 2);
  short* Wcat2  = (short*)alloc((size_t)NL * 384 * 768 * 2);
  float* SC     = (float*)alloc((size_t)NN * 4 * 4);
  float* w_e    = (float*)alloc((size_t)NE * 4);
  int*   meta   = (int*)alloc((size_t)NE * 4);
  float* wsort  = (float*)alloc((size_t)NE * 4);
  int*   rp2    = (int*)alloc((size_t)(NN * 4 + 1) * 4);
  int*   cursor = (int*)alloc((size_t)NN * 4 * 4);
  float* ninv   = (float*)alloc((size_t)NN * 4);
  char*  zb     = (char*)alloc(134144);  // musum|msqsum|c_rel contiguous, zeroed
  float* musum  = (float*)(zb);
  float* msqsum = (float*)(zb + 1536);
  int*   c_rel  = (int*)(zb + 3072);

  hipMemsetAsync(zb, 0, 134144, stream);
  k_colstats<<<256, 384, 0, stream>>>(x, musum, msqsum);
  k_bn<<<NN, 64, 0, stream>>>(x, gamma, beta, musum, msqsum, h, h_bf, ninv);
  k_counts<<<NE / 256, 256, 0, stream>>>(ei, et, c_rel);
  k_scan<<<1, 1024, 0, stream>>>(c_rel, rp2, cursor);
  k_we<<<2048, 256, 0, stream>>>(h_bf, ninv, ei, w_e);
  k_fill<<<NE / 256, 256, 0, stream>>>(ei, et, w_e, cursor, meta, wsort);
  k_packall<<<(NL * 384 * 1536 + NL * 384 * 768 + 255) / 256, 256, 0, stream>>>(
      W_rel, W_msg, W_self, Wcat, Wcat2);

  for (int l = 0; l < NL; ++l) {
    k_aggrel<<<NN, 384, 0, stream>>>(h_bf, rp2, meta, wsort, nc, Agg, SC, l);
    k_gemm_mfma<0><<<dim3(128, 6), 256, 0, stream>>>(
        Agg, 1536, Wcat + (size_t)l * 384 * 1536, SC, b_rel + l * NR * DD,
        nullptr, nullptr, nullptr, nullptr, nullptr, B1);
    k_aggmp<<<NN, 384, 0, stream>>>(B1, rp2, meta);
    k_gemm_mfma<1><<<dim3(128, 6), 256, 0, stream>>>(
        B1, 768, Wcat2 + (size_t)l * 384 * 768, nullptr, nullptr,
        b_msg + l * DD, b_self + l * DD, rp2, h, h_bf, nullptr);
  }
  k_out<<<64, 384, 0, stream>>>(h, out);
}

// Round 6
// 308.282 us; speedup vs baseline: 2.8501x; 1.0663x over previous
//
#include <hip/hip_runtime.h>
#include <hip/hip_bf16.h>

#define NN 8192
#define DD 384
#define NE 262144
#define NR 4
#define NL 2
#define NB 64

typedef __attribute__((ext_vector_type(8))) short bf16x8;
typedef __attribute__((ext_vector_type(4))) float f32x4;

__device__ __forceinline__ unsigned short f2bf(float f) {
  unsigned u = __float_as_uint(f);
  unsigned r = (u + 0x7fffu + ((u >> 16) & 1u)) >> 16;
  return (unsigned short)r;
}
__device__ __forceinline__ unsigned pack_bf2(float lo, float hi) {
  return (unsigned)f2bf(lo) | ((unsigned)f2bf(hi) << 16);
}
__device__ __forceinline__ float bflo(unsigned u) { return __uint_as_float(u << 16); }
__device__ __forceinline__ float bfhi(unsigned u) { return __uint_as_float(u & 0xffff0000u); }
__device__ __forceinline__ void gl_lds16(const void* g, void* l) {
  __builtin_amdgcn_global_load_lds(
      (const __attribute__((address_space(1))) unsigned int*)g,
      (__attribute__((address_space(3))) unsigned int*)l, 16, 0, 0);
}
__device__ __forceinline__ float dot8(uint4 a, uint4 b) {
  return bflo(a.x) * bflo(b.x) + bfhi(a.x) * bfhi(b.x) +
         bflo(a.y) * bflo(b.y) + bfhi(a.y) * bfhi(b.y) +
         bflo(a.z) * bflo(b.z) + bfhi(a.z) * bfhi(b.z) +
         bflo(a.w) * bflo(b.w) + bfhi(a.w) * bfhi(b.w);
}

// ---------------- workspace zeroing (replaces pathological rocclr fillBuffer) ------
__global__ void k_zero(uint4* __restrict__ p, int n4) {
  int i = blockIdx.x * 256 + threadIdx.x;
  if (i < n4) p[i] = make_uint4(0, 0, 0, 0);
}

// ---------------- BatchNorm column sums (256 blocks x 32 rows) ----------------
__global__ void k_colstats(const float* __restrict__ x, float* __restrict__ musum,
                           float* __restrict__ msqsum) {
  int c = threadIdx.x;            // 384
  int r0 = blockIdx.x * 32;       // 256 blocks
  float s = 0.f, s2 = 0.f;
  for (int r = 0; r < 32; ++r) {
    float v = x[(size_t)(r0 + r) * DD + c];
    s += v; s2 += v * v;
  }
  atomicAdd(&musum[c], s);
  atomicAdd(&msqsum[c], s2);
}

// h = gamma*(x-mu)*rstd + beta ; ninv = 1/||h||_row ; h_bf = bf16(h)
__global__ void k_bn(const float* __restrict__ x, const float* __restrict__ gamma,
                     const float* __restrict__ beta, const float* __restrict__ musum,
                     const float* __restrict__ msqsum, float* __restrict__ h,
                     short* __restrict__ h_bf, float* __restrict__ ninv) {
  int n = blockIdx.x;
  int t = threadIdx.x;  // 64
  float ss = 0.f;
#pragma unroll
  for (int i = 0; i < 6; ++i) {
    int c = t + i * 64;
    float m = musum[c] * (1.f / NN);
    float var = msqsum[c] * (1.f / NN) - m * m;
    float v = gamma[c] * (x[(size_t)n * DD + c] - m) * rsqrtf(var + 1e-5f) + beta[c];
    h[(size_t)n * DD + c] = v;
    h_bf[(size_t)n * DD + c] = (short)f2bf(v);
    ss += v * v;
  }
#pragma unroll
  for (int m = 32; m; m >>= 1) ss += __shfl_xor(ss, m, 64);
  if (t == 0) ninv[n] = rsqrtf(ss);
}

// ---------------- per-(dst,rel) histogram ----------------
__global__ void k_counts(const int* __restrict__ ei, const int* __restrict__ et,
                         int* __restrict__ c_rel) {
  int e = blockIdx.x * blockDim.x + threadIdx.x;
  if (e >= NE) return;
  int dst = ei[NE + e];
  atomicAdd(&c_rel[dst * NR + et[e]], 1);
}

// exclusive scan of c_rel (32768) -> rp2[32769], cursor copy
__global__ void k_scan(const int* __restrict__ c_rel, int* __restrict__ rp2,
                       int* __restrict__ cursor) {
  __shared__ int part[1024];
  int t = threadIdx.x;
  int base = t * 32;
  int v[32]; int s = 0;
#pragma unroll
  for (int i = 0; i < 32; ++i) { v[i] = c_rel[base + i]; s += v[i]; }
  part[t] = s;
  __syncthreads();
  for (int off = 1; off < 1024; off <<= 1) {
    int add = (t >= off) ? part[t - off] : 0;
    __syncthreads();
    part[t] += add;
    __syncthreads();
  }
  int run = (t == 0) ? 0 : part[t - 1];
  if (t == 0) rp2[0] = 0;
#pragma unroll
  for (int i = 0; i < 32; ++i) {
    cursor[base + i] = run;
    run += v[i];
    rp2[base + i + 1] = run;
  }
}

// ---------------- fused edge weights + CSR fill ----------------
// 16-lane group per edge; full 384-dim dot (48 uint4, 3 per lane); lane 0 of the
// group places (src, w) directly at its sorted CSR position via cursor atomic.
__global__ void k_wefill(const short* __restrict__ hb, const float* __restrict__ ninv,
                         const int* __restrict__ ei, const int* __restrict__ et,
                         int* __restrict__ cursor, int* __restrict__ meta,
                         float* __restrict__ wsort) {
  int sl = threadIdx.x & 15;
  int grp = (blockIdx.x * blockDim.x + threadIdx.x) >> 4;
  int ngrp = (gridDim.x * blockDim.x) >> 4;
  for (int e = grp; e < NE; e += ngrp) {
    int s = ei[e], d = ei[NE + e];
    const uint4* hs = (const uint4*)(hb + (size_t)s * DD);
    const uint4* hd = (const uint4*)(hb + (size_t)d * DD);
    uint4 a0 = hs[sl], a1 = hs[16 + sl], a2 = hs[32 + sl];
    uint4 b0 = hd[sl], b1 = hd[16 + sl], b2 = hd[32 + sl];
    float acc = dot8(a0, b0) + dot8(a1, b1) + dot8(a2, b2);
#pragma unroll
    for (int m = 8; m; m >>= 1) acc += __shfl_xor(acc, m, 64);
    if (sl == 0) {
      int pos = atomicAdd(&cursor[d * NR + et[e]], 1);
      meta[pos] = s;
      wsort[pos] = acc * ninv[s] * ninv[d];
    }
  }
}

// ---------------- per-relation aggregation of h (bf16 in/out), 4-deep unroll ------
__global__ void k_aggrel(const short* __restrict__ hb, const int* __restrict__ rp2,
                         const int* __restrict__ meta, const float* __restrict__ wsort,
                         const float* __restrict__ nc, short* __restrict__ Agg,
                         float* __restrict__ SC, int layer) {
  int n = blockIdx.x;
  int t = threadIdx.x;       // 384
  int r = t / 96;            // relation group
  int i = t - r * 96;        // 0..95, owns cols [4i, 4i+4)
  int beg = rp2[n * 4 + r], end = rp2[n * 4 + r + 1];
  float a0 = 0, a1 = 0, a2 = 0, a3 = 0, s = 0;
  int e = beg;
  for (; e + 3 < end; e += 4) {
    int s0 = meta[e], s1 = meta[e + 1], s2 = meta[e + 2], s3 = meta[e + 3];
    float w0 = wsort[e], w1 = wsort[e + 1], w2 = wsort[e + 2], w3 = wsort[e + 3];
    uint2 u0 = ((const uint2*)(hb + (size_t)s0 * DD))[i];
    uint2 u1 = ((const uint2*)(hb + (size_t)s1 * DD))[i];
    uint2 u2 = ((const uint2*)(hb + (size_t)s2 * DD))[i];
    uint2 u3 = ((const uint2*)(hb + (size_t)s3 * DD))[i];
    a0 += w0 * bflo(u0.x) + w1 * bflo(u1.x) + w2 * bflo(u2.x) + w3 * bflo(u3.x);
    a1 += w0 * bfhi(u0.x) + w1 * bfhi(u1.x) + w2 * bfhi(u2.x) + w3 * bfhi(u3.x);
    a2 += w0 * bflo(u0.y) + w1 * bflo(u1.y) + w2 * bflo(u2.y) + w3 * bflo(u3.y);
    a3 += w0 * bfhi(u0.y) + w1 * bfhi(u1.y) + w2 * bfhi(u2.y) + w3 * bfhi(u3.y);
    s += w0 + w1 + w2 + w3;
  }
  for (; e < end; ++e) {
    int s0 = meta[e];
    float w0 = wsort[e];
    uint2 u0 = ((const uint2*)(hb + (size_t)s0 * DD))[i];
    a0 += w0 * bflo(u0.x); a1 += w0 * bfhi(u0.x);
    a2 += w0 * bflo(u0.y); a3 += w0 * bfhi(u0.y);
    s += w0;
  }
  int c = end - beg;
  float f = 1.f / (nc[layer * 4 + r] * (float)(c > 1 ? c : 1));
  uint2 o;
  o.x = pack_bf2(a0 * f, a1 * f);
  o.y = pack_bf2(a2 * f, a3 * f);
  ((uint2*)(Agg + (size_t)n * 1536 + r * 384))[i] = o;
  if (i == 0) SC[n * 4 + r] = s * f;
}

// ---------------- MP mean aggregation of rel_out (bf16), 4-deep unroll ------------
__global__ void k_aggmp(short* __restrict__ B1, const int* __restrict__ rp2,
                        const int* __restrict__ meta) {
  __shared__ float red[3][96][4];
  int n = blockIdx.x;
  int t = threadIdx.x;  // 384
  int g = t / 96, i = t - g * 96;
  int beg = rp2[n * 4], end = rp2[n * 4 + 4];
  float a0 = 0, a1 = 0, a2 = 0, a3 = 0;
  int e = beg + g;
  for (; e + 12 < end; e += 16) {
    int s0 = meta[e], s1 = meta[e + 4], s2 = meta[e + 8], s3 = meta[e + 12];
    uint2 u0 = ((const uint2*)(B1 + (size_t)s0 * 768 + 384))[i];
    uint2 u1 = ((const uint2*)(B1 + (size_t)s1 * 768 + 384))[i];
    uint2 u2 = ((const uint2*)(B1 + (size_t)s2 * 768 + 384))[i];
    uint2 u3 = ((const uint2*)(B1 + (size_t)s3 * 768 + 384))[i];
    a0 += bflo(u0.x) + bflo(u1.x) + bflo(u2.x) + bflo(u3.x);
    a1 += bfhi(u0.x) + bfhi(u1.x) + bfhi(u2.x) + bfhi(u3.x);
    a2 += bflo(u0.y) + bflo(u1.y) + bflo(u2.y) + bflo(u3.y);
    a3 += bfhi(u0.y) + bfhi(u1.y) + bfhi(u2.y) + bfhi(u3.y);
  }
  for (; e < end; e += 4) {
    int s0 = meta[e];
    uint2 u = ((const uint2*)(B1 + (size_t)s0 * 768 + 384))[i];
    a0 += bflo(u.x); a1 += bfhi(u.x);
    a2 += bflo(u.y); a3 += bfhi(u.y);
  }
  if (g) {
    red[g - 1][i][0] = a0; red[g - 1][i][1] = a1;
    red[g - 1][i][2] = a2; red[g - 1][i][3] = a3;
  }
  __syncthreads();
  if (g == 0) {
#pragma unroll
    for (int k = 0; k < 3; ++k) {
      a0 += red[k][i][0]; a1 += red[k][i][1];
      a2 += red[k][i][2]; a3 += red[k][i][3];
    }
    float inv = (end > beg) ? 1.f / (float)(end - beg) : 0.f;
    uint2 o;
    o.x = pack_bf2(a0 * inv, a1 * inv);
    o.y = pack_bf2(a2 * inv, a3 * inv);
    ((uint2*)(B1 + (size_t)n * 768))[i] = o;
  }
}

// ---------------- weight packing, both layers in one dispatch ----------------
__global__ void k_packall(const float* __restrict__ W_rel, const float* __restrict__ W_msg,
                          const float* __restrict__ W_self, short* __restrict__ Wcat,
                          short* __restrict__ Wcat2) {
  const int T1 = NL * 384 * 1536;
  const int T2 = NL * 384 * 768;
  int idx = blockIdx.x * blockDim.x + threadIdx.x;
  if (idx < T1) {
    int l = idx / (384 * 1536);
    int rem = idx - l * 384 * 1536;
    int i = rem / 1536, kk = rem - i * 1536;
    int r = kk / 384, k = kk - r * 384;
    Wcat[idx] = (short)f2bf(W_rel[(((size_t)(l * NR + r) * DD) + i) * DD + k]);
  } else if (idx < T1 + T2) {
    int j = idx - T1;
    int l = j / (384 * 768);
    int rem = j - l * 384 * 768;
    int i = rem / 768, kk = rem - i * 768;
    float v = (kk < 384) ? W_msg[((size_t)l * DD + i) * DD + kk]
                         : W_self[((size_t)l * DD + i) * DD + kk - 384];
    Wcat2[j] = (short)f2bf(v);
  }
}

// ---------------- bf16 MFMA NT GEMM: C[8192 x 384] = A[8192 x K] * Bp[384 x K]^T --------
// 64x64 tile, 4 waves (each 32x32), BK=64, global_load_lds w=16, XOR-swizzled LDS
// (pre-swizzled global source + swizzled ds_read; LDS dest linear — rule #21).
// MODE 0: C = relu(acc + sum_r SC[row][r]*b_rel[r][col]) -> bf16 B1[:,384:768]
// MODE 1: h = relu(acc + deg?b_msg + b_self) + h  (fp32), also h_bf = bf16(h)
template <int MODE>
__global__ __launch_bounds__(256) void k_gemm_mfma(
    const short* __restrict__ A, int K, const short* __restrict__ Bp,
    const float* __restrict__ SC, const float* __restrict__ brel_l,
    const float* __restrict__ bmsg_l, const float* __restrict__ bself_l,
    const int* __restrict__ rp2, float* __restrict__ h,
    short* __restrict__ h_bf, short* __restrict__ Cout) {
  __shared__ short As[64 * 64];   // 8KB each: row-major 64 rows x 8 chunks(16B)
  __shared__ short Bs[64 * 64];   // chunk q' of row r holds global chunk q'^(r&7)
  int tid = threadIdx.x;
  int lane = tid & 63;
  int w = tid >> 6;              // 0..3
  int wr = w >> 1, wc = w & 1;   // wave tile origin (wr*32, wc*32)
  int bm = blockIdx.x, bn = blockIdx.y;

  // staging: wave w, set s covers chunks s*256 + w*64 + lane
  // -> row r = chunk>>3, slot q' = lane&7, global col-chunk q = q'^(r&7)
  int r0 = (w << 3) + (lane >> 3);        // rows 0..31 (set 0); set 1 adds 32
  int qg = (lane & 7) ^ (r0 & 7);         // (r0+32)&7 == r0&7
  const short* Ag0 = A + (size_t)(bm * 64 + r0) * K + qg * 8;
  const short* Ag1 = A + (size_t)(bm * 64 + r0 + 32) * K + qg * 8;
  const short* Bg0 = Bp + (size_t)(bn * 64 + r0) * K + qg * 8;
  const short* Bg1 = Bp + (size_t)(bn * 64 + r0 + 32) * K + qg * 8;
  short* Asl0 = As + w * 512;             // wave-uniform bases; lane*16B added by HW
  short* Asl1 = As + 2048 + w * 512;
  short* Bsl0 = Bs + w * 512;
  short* Bsl1 = Bs + 2048 + w * 512;

  f32x4 acc[2][2] = {};
  int fr = lane & 15, fq = lane >> 4;  // fragment row, k-chunk within 32-k block
  for (int k0 = 0; k0 < K; k0 += 64) {
    __syncthreads();
    gl_lds16(Ag0 + k0, Asl0);
    gl_lds16(Ag1 + k0, Asl1);
    gl_lds16(Bg0 + k0, Bsl0);
    gl_lds16(Bg1 + k0, Bsl1);
    __syncthreads();
#pragma unroll
    for (int kk = 0; kk < 2; ++kk) {
      bf16x8 a[2], b[2];
#pragma unroll
      for (int i = 0; i < 2; ++i) {
        int r = wr * 32 + i * 16 + fr;
        int qs = (kk * 4 + fq) ^ (r & 7);
        a[i] = *(const bf16x8*)&As[r * 64 + qs * 8];
      }
#pragma unroll
      for (int j = 0; j < 2; ++j) {
        int r = wc * 32 + j * 16 + fr;
        int qs = (kk * 4 + fq) ^ (r & 7);
        b[j] = *(const bf16x8*)&Bs[r * 64 + qs * 8];
      }
#pragma unroll
      for (int i = 0; i < 2; ++i)
#pragma unroll
        for (int j = 0; j < 2; ++j)
          acc[i][j] = __builtin_amdgcn_mfma_f32_16x16x32_bf16(a[i], b[j], acc[i][j], 0, 0, 0);
    }
  }

  // epilogue: C/D layout col=lane&15, row=(lane>>4)*4+reg
  int cr = (lane >> 4) * 4;
  int cc = lane & 15;
#pragma unroll
  for (int i = 0; i < 2; ++i) {
#pragma unroll
    for (int jj = 0; jj < 4; ++jj) {
      int row = bm * 64 + wr * 32 + i * 16 + cr + jj;
      if (MODE == 0) {
        float4 sc = *(const float4*)&SC[row * 4];
#pragma unroll
        for (int j = 0; j < 2; ++j) {
          int col = bn * 64 + wc * 32 + j * 16 + cc;
          float v = acc[i][j][jj] + sc.x * brel_l[col] + sc.y * brel_l[384 + col] +
                    sc.z * brel_l[768 + col] + sc.w * brel_l[1152 + col];
          Cout[(size_t)row * 768 + 384 + col] = (short)f2bf(fmaxf(v, 0.f));
        }
      } else {
        float bmul = (rp2[(row + 1) * 4] > rp2[row * 4]) ? 1.f : 0.f;
#pragma unroll
        for (int j = 0; j < 2; ++j) {
          int col = bn * 64 + wc * 32 + j * 16 + cc;
          float v = acc[i][j][jj] + bmul * bmsg_l[col] + bself_l[col];
          float o = fmaxf(v, 0.f) + h[(size_t)row * DD + col];
          h[(size_t)row * DD + col] = o;
          h_bf[(size_t)row * DD + col] = (short)f2bf(o);
        }
      }
    }
  }
}

// ---------------- final per-batch mean ----------------
__global__ void k_out(const float* __restrict__ h, float* __restrict__ out) {
  int b = blockIdx.x;   // 64
  int c = threadIdx.x;  // 384
  float s = 0.f;
  for (int j = 0; j < 128; ++j) s += h[(size_t)(b * 128 + j) * DD + c];
  out[b * DD + c] = s * (1.f / 128.f);
}

extern "C" void kernel_launch(void* const* d_in, const int* in_sizes, int n_in,
                              void* d_out, int out_size, void* d_ws, size_t ws_size,
                              hipStream_t stream) {
  const float* x      = (const float*)d_in[0];
  const int*   ei     = (const int*)d_in[1];
  const int*   et     = (const int*)d_in[2];
  const float* gamma  = (const float*)d_in[3];
  const float* beta   = (const float*)d_in[4];
  const float* W_rel  = (const float*)d_in[5];
  const float* b_rel  = (const float*)d_in[6];
  const float* nc     = (const float*)d_in[7];
  const float* W_msg  = (const float*)d_in[8];
  const float* b_msg  = (const float*)d_in[9];
  const float* W_self = (const float*)d_in[10];
  const float* b_self = (const float*)d_in[11];
  float* out = (float*)d_out;

  char* ws = (char*)d_ws;
  size_t off = 0;
  auto alloc = [&](size_t bytes) -> void* {
    void* p = ws + off;
    off = (off + bytes + 255) & ~(size_t)255;
    return p;
  };
  float* h      = (float*)alloc((size_t)NN * DD * 4);
  short* h_bf   = (short*)alloc((size_t)NN * DD * 2);
  short* Agg    = (short*)alloc((size_t)NN * 1536 * 2);
  short* B1     = (short*)alloc((size_t)NN * 768 * 2);
  short* Wcat   = (short*)alloc((size_t)NL * 384 * 1536 * 2);
  short* Wcat2  = (short*)alloc((size_t)NL * 384 * 768 * 2);
  float* SC     = (float*)alloc((size_t)NN * 4 * 4);
  int*   meta   = (int*)alloc((size_t)NE * 4);
  float* wsort  = (float*)alloc((size_t)NE * 4);
  int*   rp2    = (int*)alloc((size_t)(NN * 4 + 1) * 4);
  int*   cursor = (int*)alloc((size_t)NN * 4 * 4);
  float* ninv   = (float*)alloc((size_t)NN * 4);
  char*  zb     = (char*)alloc(134144);  // musum|msqsum|c_rel contiguous, zeroed
  float* musum  = (float*)(zb);
  float* msqsum = (float*)(zb + 1536);
  int*   c_rel  = (int*)(zb + 3072);

  k_zero<<<(134144 / 16 + 255) / 256, 256, 0, stream>>>((uint4*)zb, 134144 / 16);
  k_colstats<<<256, 384, 0, stream>>>(x, musum, msqsum);
  k_bn<<<NN, 64, 0, stream>>>(x, gamma, beta, musum, msqsum, h, h_bf, ninv);
  k_counts<<<NE / 256, 256, 0, stream>>>(ei, et, c_rel);
  k_scan<<<1, 1024, 0, stream>>>(c_rel, rp2, cursor);
  k_wefill<<<2048, 256, 0, stream>>>(h_bf, ninv, ei, et, cursor, meta, wsort);
  k_packall<<<(NL * 384 * 1536 + NL * 384 * 768 + 255) / 256, 256, 0, stream>>>(
      W_rel, W_msg, W_self, Wcat, Wcat2);

  for (int l = 0; l < NL; ++l) {
    k_aggrel<<<NN, 384, 0, stream>>>(h_bf, rp2, meta, wsort, nc, Agg, SC, l);
    k_gemm_mfma<0><<<dim3(128, 6), 256, 0, stream>>>(
        Agg, 1536, Wcat + (size_t)l * 384 * 1536, SC, b_rel + l * NR * DD,
        nullptr, nullptr, nullptr, nullptr, nullptr, B1);
    k_aggmp<<<NN, 384, 0, stream>>>(B1, rp2, meta);
    k_gemm_mfma<1><<<dim3(128, 6), 256, 0, stream>>>(
        B1, 768, Wcat2 + (size_t)l * 384 * 768, nullptr, nullptr,
        b_msg + l * DD, b_self + l * DD, rp2, h, h_bf, nullptr);
  }
  k_out<<<64, 384, 0, stream>>>(h, out);
}

// Round 7
// 304.322 us; speedup vs baseline: 2.8872x; 1.0130x over previous
//
#include <hip/hip_runtime.h>
#include <hip/hip_bf16.h>

#define NN 8192
#define DD 384
#define NE 262144
#define NR 4
#define NL 2
#define NB 64

typedef __attribute__((ext_vector_type(8))) short bf16x8;
typedef __attribute__((ext_vector_type(4))) float f32x4;

__device__ __forceinline__ unsigned short f2bf(float f) {
  unsigned u = __float_as_uint(f);
  unsigned r = (u + 0x7fffu + ((u >> 16) & 1u)) >> 16;
  return (unsigned short)r;
}
__device__ __forceinline__ unsigned pack_bf2(float lo, float hi) {
  return (unsigned)f2bf(lo) | ((unsigned)f2bf(hi) << 16);
}
__device__ __forceinline__ float bflo(unsigned u) { return __uint_as_float(u << 16); }
__device__ __forceinline__ float bfhi(unsigned u) { return __uint_as_float(u & 0xffff0000u); }
__device__ __forceinline__ void gl_lds16(const void* g, void* l) {
  __builtin_amdgcn_global_load_lds(
      (const __attribute__((address_space(1))) unsigned int*)g,
      (__attribute__((address_space(3))) unsigned int*)l, 16, 0, 0);
}
__device__ __forceinline__ float dot8(uint4 a, uint4 b) {
  return bflo(a.x) * bflo(b.x) + bfhi(a.x) * bfhi(b.x) +
         bflo(a.y) * bflo(b.y) + bfhi(a.y) * bfhi(b.y) +
         bflo(a.z) * bflo(b.z) + bfhi(a.z) * bfhi(b.z) +
         bflo(a.w) * bflo(b.w) + bfhi(a.w) * bfhi(b.w);
}

// ---------------- workspace zeroing ----------------
__global__ void k_zero(uint4* __restrict__ p, int n4) {
  int i = blockIdx.x * 256 + threadIdx.x;
  if (i < n4) p[i] = make_uint4(0, 0, 0, 0);
}

// ---------------- BatchNorm column sums (256 blocks x 32 rows) ----------------
__global__ void k_colstats(const float* __restrict__ x, float* __restrict__ musum,
                           float* __restrict__ msqsum) {
  int c = threadIdx.x;            // 384
  int r0 = blockIdx.x * 32;       // 256 blocks
  float s = 0.f, s2 = 0.f;
  for (int r = 0; r < 32; ++r) {
    float v = x[(size_t)(r0 + r) * DD + c];
    s += v; s2 += v * v;
  }
  atomicAdd(&musum[c], s);
  atomicAdd(&msqsum[c], s2);
}

// h = gamma*(x-mu)*rstd + beta ; ninv = 1/||h||_row ; h_bf = bf16(h)
__global__ void k_bn(const float* __restrict__ x, const float* __restrict__ gamma,
                     const float* __restrict__ beta, const float* __restrict__ musum,
                     const float* __restrict__ msqsum, float* __restrict__ h,
                     short* __restrict__ h_bf, float* __restrict__ ninv) {
  int n = blockIdx.x;
  int t = threadIdx.x;  // 64
  float ss = 0.f;
#pragma unroll
  for (int i = 0; i < 6; ++i) {
    int c = t + i * 64;
    float m = musum[c] * (1.f / NN);
    float var = msqsum[c] * (1.f / NN) - m * m;
    float v = gamma[c] * (x[(size_t)n * DD + c] - m) * rsqrtf(var + 1e-5f) + beta[c];
    h[(size_t)n * DD + c] = v;
    h_bf[(size_t)n * DD + c] = (short)f2bf(v);
    ss += v * v;
  }
#pragma unroll
  for (int m = 32; m; m >>= 1) ss += __shfl_xor(ss, m, 64);
  if (t == 0) ninv[n] = rsqrtf(ss);
}

// ---------------- per-(dst,rel) histogram ----------------
__global__ void k_counts(const int* __restrict__ ei, const int* __restrict__ et,
                         int* __restrict__ c_rel) {
  int e = blockIdx.x * blockDim.x + threadIdx.x;
  if (e >= NE) return;
  int dst = ei[NE + e];
  atomicAdd(&c_rel[dst * NR + et[e]], 1);
}

// exclusive scan of c_rel (32768) -> rp2[32769], cursor copy
__global__ void k_scan(const int* __restrict__ c_rel, int* __restrict__ rp2,
                       int* __restrict__ cursor) {
  __shared__ int part[1024];
  int t = threadIdx.x;
  int base = t * 32;
  int v[32]; int s = 0;
#pragma unroll
  for (int i = 0; i < 32; ++i) { v[i] = c_rel[base + i]; s += v[i]; }
  part[t] = s;
  __syncthreads();
  for (int off = 1; off < 1024; off <<= 1) {
    int add = (t >= off) ? part[t - off] : 0;
    __syncthreads();
    part[t] += add;
    __syncthreads();
  }
  int run = (t == 0) ? 0 : part[t - 1];
  if (t == 0) rp2[0] = 0;
#pragma unroll
  for (int i = 0; i < 32; ++i) {
    cursor[base + i] = run;
    run += v[i];
    rp2[base + i + 1] = run;
  }
}

// ---------------- CSR fill (sorted by dst, then relation) — no weights ----------
__global__ void k_fill(const int* __restrict__ ei, const int* __restrict__ et,
                       int* __restrict__ cursor, int* __restrict__ meta) {
  int e = blockIdx.x * blockDim.x + threadIdx.x;
  if (e >= NE) return;
  int src = ei[e], dst = ei[NE + e];
  int pos = atomicAdd(&cursor[dst * NR + et[e]], 1);
  meta[pos] = src;
}

// ---------------- edge cosine weights over sorted CSR (dst-local) --------------
// One block per dst node; 16 groups of 16 lanes; dst row L1-broadcast across
// groups; wsort written in place (slot index), no atomics.
__global__ void k_we2(const short* __restrict__ hb, const float* __restrict__ ninv,
                      const int* __restrict__ rp2, const int* __restrict__ meta,
                      float* __restrict__ wsort) {
  int n = blockIdx.x;
  int g = threadIdx.x >> 4, sl = threadIdx.x & 15;  // 256 threads
  int beg = rp2[n * 4], end = rp2[n * 4 + 4];
  if (beg == end) return;
  const uint4* hd = (const uint4*)(hb + (size_t)n * DD);
  uint4 b0 = hd[sl], b1 = hd[16 + sl], b2 = hd[32 + sl];
  float nd = ninv[n];
  for (int s = beg + g; s < end; s += 16) {
    int src = meta[s];
    const uint4* hs = (const uint4*)(hb + (size_t)src * DD);
    float acc = dot8(hs[sl], b0) + dot8(hs[16 + sl], b1) + dot8(hs[32 + sl], b2);
#pragma unroll
    for (int m = 8; m; m >>= 1) acc += __shfl_xor(acc, m, 64);
    if (sl == 0) wsort[s] = acc * ninv[src] * nd;
  }
}

// ---------------- per-relation aggregation of h (bf16 in/out), 4-deep unroll ------
__global__ void k_aggrel(const short* __restrict__ hb, const int* __restrict__ rp2,
                         const int* __restrict__ meta, const float* __restrict__ wsort,
                         const float* __restrict__ nc, short* __restrict__ Agg,
                         float* __restrict__ SC, int layer) {
  int n = blockIdx.x;
  int t = threadIdx.x;       // 384
  int r = t / 96;            // relation group
  int i = t - r * 96;        // 0..95, owns cols [4i, 4i+4)
  int beg = rp2[n * 4 + r], end = rp2[n * 4 + r + 1];
  float a0 = 0, a1 = 0, a2 = 0, a3 = 0, s = 0;
  int e = beg;
  for (; e + 3 < end; e += 4) {
    int s0 = meta[e], s1 = meta[e + 1], s2 = meta[e + 2], s3 = meta[e + 3];
    float w0 = wsort[e], w1 = wsort[e + 1], w2 = wsort[e + 2], w3 = wsort[e + 3];
    uint2 u0 = ((const uint2*)(hb + (size_t)s0 * DD))[i];
    uint2 u1 = ((const uint2*)(hb + (size_t)s1 * DD))[i];
    uint2 u2 = ((const uint2*)(hb + (size_t)s2 * DD))[i];
    uint2 u3 = ((const uint2*)(hb + (size_t)s3 * DD))[i];
    a0 += w0 * bflo(u0.x) + w1 * bflo(u1.x) + w2 * bflo(u2.x) + w3 * bflo(u3.x);
    a1 += w0 * bfhi(u0.x) + w1 * bfhi(u1.x) + w2 * bfhi(u2.x) + w3 * bfhi(u3.x);
    a2 += w0 * bflo(u0.y) + w1 * bflo(u1.y) + w2 * bflo(u2.y) + w3 * bflo(u3.y);
    a3 += w0 * bfhi(u0.y) + w1 * bfhi(u1.y) + w2 * bfhi(u2.y) + w3 * bfhi(u3.y);
    s += w0 + w1 + w2 + w3;
  }
  for (; e < end; ++e) {
    int s0 = meta[e];
    float w0 = wsort[e];
    uint2 u0 = ((const uint2*)(hb + (size_t)s0 * DD))[i];
    a0 += w0 * bflo(u0.x); a1 += w0 * bfhi(u0.x);
    a2 += w0 * bflo(u0.y); a3 += w0 * bfhi(u0.y);
    s += w0;
  }
  int c = end - beg;
  float f = 1.f / (nc[layer * 4 + r] * (float)(c > 1 ? c : 1));
  uint2 o;
  o.x = pack_bf2(a0 * f, a1 * f);
  o.y = pack_bf2(a2 * f, a3 * f);
  ((uint2*)(Agg + (size_t)n * 1536 + r * 384))[i] = o;
  if (i == 0) SC[n * 4 + r] = s * f;
}

// ---------------- MP mean aggregation of rel_out (bf16), 4-deep unroll ------------
__global__ void k_aggmp(short* __restrict__ B1, const int* __restrict__ rp2,
                        const int* __restrict__ meta) {
  __shared__ float red[3][96][4];
  int n = blockIdx.x;
  int t = threadIdx.x;  // 384
  int g = t / 96, i = t - g * 96;
  int beg = rp2[n * 4], end = rp2[n * 4 + 4];
  float a0 = 0, a1 = 0, a2 = 0, a3 = 0;
  int e = beg + g;
  for (; e + 12 < end; e += 16) {
    int s0 = meta[e], s1 = meta[e + 4], s2 = meta[e + 8], s3 = meta[e + 12];
    uint2 u0 = ((const uint2*)(B1 + (size_t)s0 * 768 + 384))[i];
    uint2 u1 = ((const uint2*)(B1 + (size_t)s1 * 768 + 384))[i];
    uint2 u2 = ((const uint2*)(B1 + (size_t)s2 * 768 + 384))[i];
    uint2 u3 = ((const uint2*)(B1 + (size_t)s3 * 768 + 384))[i];
    a0 += bflo(u0.x) + bflo(u1.x) + bflo(u2.x) + bflo(u3.x);
    a1 += bfhi(u0.x) + bfhi(u1.x) + bfhi(u2.x) + bfhi(u3.x);
    a2 += bflo(u0.y) + bflo(u1.y) + bflo(u2.y) + bflo(u3.y);
    a3 += bfhi(u0.y) + bfhi(u1.y) + bfhi(u2.y) + bfhi(u3.y);
  }
  for (; e < end; e += 4) {
    int s0 = meta[e];
    uint2 u = ((const uint2*)(B1 + (size_t)s0 * 768 + 384))[i];
    a0 += bflo(u.x); a1 += bfhi(u.x);
    a2 += bflo(u.y); a3 += bfhi(u.y);
  }
  if (g) {
    red[g - 1][i][0] = a0; red[g - 1][i][1] = a1;
    red[g - 1][i][2] = a2; red[g - 1][i][3] = a3;
  }
  __syncthreads();
  if (g == 0) {
#pragma unroll
    for (int k = 0; k < 3; ++k) {
      a0 += red[k][i][0]; a1 += red[k][i][1];
      a2 += red[k][i][2]; a3 += red[k][i][3];
    }
    float inv = (end > beg) ? 1.f / (float)(end - beg) : 0.f;
    uint2 o;
    o.x = pack_bf2(a0 * inv, a1 * inv);
    o.y = pack_bf2(a2 * inv, a3 * inv);
    ((uint2*)(B1 + (size_t)n * 768))[i] = o;
  }
}

// ---------------- weight packing, both layers in one dispatch ----------------
__global__ void k_packall(const float* __restrict__ W_rel, const float* __restrict__ W_msg,
                          const float* __restrict__ W_self, short* __restrict__ Wcat,
                          short* __restrict__ Wcat2) {
  const int T1 = NL * 384 * 1536;
  const int T2 = NL * 384 * 768;
  int idx = blockIdx.x * blockDim.x + threadIdx.x;
  if (idx < T1) {
    int l = idx / (384 * 1536);
    int rem = idx - l * 384 * 1536;
    int i = rem / 1536, kk = rem - i * 1536;
    int r = kk / 384, k = kk - r * 384;
    Wcat[idx] = (short)f2bf(W_rel[(((size_t)(l * NR + r) * DD) + i) * DD + k]);
  } else if (idx < T1 + T2) {
    int j = idx - T1;
    int l = j / (384 * 768);
    int rem = j - l * 384 * 768;
    int i = rem / 768, kk = rem - i * 768;
    float v = (kk < 384) ? W_msg[((size_t)l * DD + i) * DD + kk]
                         : W_self[((size_t)l * DD + i) * DD + kk - 384];
    Wcat2[j] = (short)f2bf(v);
  }
}

// ---------------- bf16 MFMA NT GEMM, double-buffered single-barrier pipeline ------
// 64x64 tile, 4 waves (each 32x32), BK=64, global_load_lds w=16, XOR-swizzled LDS
// (pre-swizzled global source + swizzled ds_read; LDS dest linear — rule #21).
// Per iter: STAGE(next buf) || ds_read+MFMA(cur buf); one __syncthreads() drains both.
// MODE 0: C = relu(acc + sum_r SC[row][r]*b_rel[r][col]) -> bf16 B1[:,384:768]
// MODE 1: h = relu(acc + deg?b_msg + b_self) + h  (fp32), also h_bf = bf16(h)
template <int MODE>
__global__ __launch_bounds__(256) void k_gemm_mfma(
    const short* __restrict__ A, int K, const short* __restrict__ Bp,
    const float* __restrict__ SC, const float* __restrict__ brel_l,
    const float* __restrict__ bmsg_l, const float* __restrict__ bself_l,
    const int* __restrict__ rp2, float* __restrict__ h,
    short* __restrict__ h_bf, short* __restrict__ Cout) {
  __shared__ short As[2][64 * 64];   // 8KB per buffer: 64 rows x 8 chunks(16B)
  __shared__ short Bs[2][64 * 64];   // chunk q' of row r holds global chunk q'^(r&7)
  int tid = threadIdx.x;
  int lane = tid & 63;
  int w = tid >> 6;              // 0..3
  int wr = w >> 1, wc = w & 1;   // wave tile origin (wr*32, wc*32)
  int bm = blockIdx.x, bn = blockIdx.y;

  // staging: row r = chunk>>3, slot q' = lane&7, global col-chunk q = q'^(r&7)
  int r0 = (w << 3) + (lane >> 3);        // rows 0..31 (set 0); set 1 adds 32
  int qg = (lane & 7) ^ (r0 & 7);         // (r0+32)&7 == r0&7
  const short* Ag0 = A + (size_t)(bm * 64 + r0) * K + qg * 8;
  const short* Ag1 = A + (size_t)(bm * 64 + r0 + 32) * K + qg * 8;
  const short* Bg0 = Bp + (size_t)(bn * 64 + r0) * K + qg * 8;
  const short* Bg1 = Bp + (size_t)(bn * 64 + r0 + 32) * K + qg * 8;

  auto stage = [&](int bi, int k0) {
    gl_lds16(Ag0 + k0, &As[bi][w * 512]);           // wave-uniform bases
    gl_lds16(Ag1 + k0, &As[bi][2048 + w * 512]);    // (lane*16B added by HW)
    gl_lds16(Bg0 + k0, &Bs[bi][w * 512]);
    gl_lds16(Bg1 + k0, &Bs[bi][2048 + w * 512]);
  };

  f32x4 acc[2][2] = {};
  int fr = lane & 15, fq = lane >> 4;  // fragment row, k-chunk within 32-k block
  int nt = K >> 6;
  stage(0, 0);
  __syncthreads();
  for (int t = 0; t < nt; ++t) {
    if (t + 1 < nt) stage((t + 1) & 1, (t + 1) << 6);
    const short* Ab = As[t & 1];
    const short* Bb = Bs[t & 1];
#pragma unroll
    for (int kk = 0; kk < 2; ++kk) {
      bf16x8 a[2], b[2];
#pragma unroll
      for (int i = 0; i < 2; ++i) {
        int r = wr * 32 + i * 16 + fr;
        int qs = (kk * 4 + fq) ^ (r & 7);
        a[i] = *(const bf16x8*)&Ab[r * 64 + qs * 8];
      }
#pragma unroll
      for (int j = 0; j < 2; ++j) {
        int r = wc * 32 + j * 16 + fr;
        int qs = (kk * 4 + fq) ^ (r & 7);
        b[j] = *(const bf16x8*)&Bb[r * 64 + qs * 8];
      }
#pragma unroll
      for (int i = 0; i < 2; ++i)
#pragma unroll
        for (int j = 0; j < 2; ++j)
          acc[i][j] = __builtin_amdgcn_mfma_f32_16x16x32_bf16(a[i], b[j], acc[i][j], 0, 0, 0);
    }
    __syncthreads();  // drains stage (vmcnt) + this tile's ds_reads (lgkmcnt)
  }

  // epilogue: C/D layout col=lane&15, row=(lane>>4)*4+reg
  int cr = (lane >> 4) * 4;
  int cc = lane & 15;
#pragma unroll
  for (int i = 0; i < 2; ++i) {
#pragma unroll
    for (int jj = 0; jj < 4; ++jj) {
      int row = bm * 64 + wr * 32 + i * 16 + cr + jj;
      if (MODE == 0) {
        float4 sc = *(const float4*)&SC[row * 4];
#pragma unroll
        for (int j = 0; j < 2; ++j) {
          int col = bn * 64 + wc * 32 + j * 16 + cc;
          float v = acc[i][j][jj] + sc.x * brel_l[col] + sc.y * brel_l[384 + col] +
                    sc.z * brel_l[768 + col] + sc.w * brel_l[1152 + col];
          Cout[(size_t)row * 768 + 384 + col] = (short)f2bf(fmaxf(v, 0.f));
        }
      } else {
        float bmul = (rp2[(row + 1) * 4] > rp2[row * 4]) ? 1.f : 0.f;
#pragma unroll
        for (int j = 0; j < 2; ++j) {
          int col = bn * 64 + wc * 32 + j * 16 + cc;
          float v = acc[i][j][jj] + bmul * bmsg_l[col] + bself_l[col];
          float o = fmaxf(v, 0.f) + h[(size_t)row * DD + col];
          h[(size_t)row * DD + col] = o;
          h_bf[(size_t)row * DD + col] = (short)f2bf(o);
        }
      }
    }
  }
}

// ---------------- final per-batch mean ----------------
__global__ void k_out(const float* __restrict__ h, float* __restrict__ out) {
  int b = blockIdx.x;   // 64
  int c = threadIdx.x;  // 384
  float s = 0.f;
  for (int j = 0; j < 128; ++j) s += h[(size_t)(b * 128 + j) * DD + c];
  out[b * DD + c] = s * (1.f / 128.f);
}

extern "C" void kernel_launch(void* const* d_in, const int* in_sizes, int n_in,
                              void* d_out, int out_size, void* d_ws, size_t ws_size,
                              hipStream_t stream) {
  const float* x      = (const float*)d_in[0];
  const int*   ei     = (const int*)d_in[1];
  const int*   et     = (const int*)d_in[2];
  const float* gamma  = (const float*)d_in[3];
  const float* beta   = (const float*)d_in[4];
  const float* W_rel  = (const float*)d_in[5];
  const float* b_rel  = (const float*)d_in[6];
  const float* nc     = (const float*)d_in[7];
  const float* W_msg  = (const float*)d_in[8];
  const float* b_msg  = (const float*)d_in[9];
  const float* W_self = (const float*)d_in[10];
  const float* b_self = (const float*)d_in[11];
  float* out = (float*)d_out;

  char* ws = (char*)d_ws;
  size_t off = 0;
  auto alloc = [&](size_t bytes) -> void* {
    void* p = ws + off;
    off = (off + bytes + 255) & ~(size_t)255;
    return p;
  };
  float* h      = (float*)alloc((size_t)NN * DD * 4);
  short* h_bf   = (short*)alloc((size_t)NN * DD * 2);
  short* Agg    = (short*)alloc((size_t)NN * 1536 * 2);
  short* B1     = (short*)alloc((size_t)NN * 768 * 2);
  short* Wcat   = (short*)alloc((size_t)NL * 384 * 1536 * 2);
  short* Wcat2  = (short*)alloc((size_t)NL * 384 * 768 * 2);
  float* SC     = (float*)alloc((size_t)NN * 4 * 4);
  int*   meta   = (int*)alloc((size_t)NE * 4);
  float* wsort  = (float*)alloc((size_t)NE * 4);
  int*   rp2    = (int*)alloc((size_t)(NN * 4 + 1) * 4);
  int*   cursor = (int*)alloc((size_t)NN * 4 * 4);
  float* ninv   = (float*)alloc((size_t)NN * 4);
  char*  zb     = (char*)alloc(134144);  // musum|msqsum|c_rel contiguous, zeroed
  float* musum  = (float*)(zb);
  float* msqsum = (float*)(zb + 1536);
  int*   c_rel  = (int*)(zb + 3072);

  k_zero<<<(134144 / 16 + 255) / 256, 256, 0, stream>>>((uint4*)zb, 134144 / 16);
  k_colstats<<<256, 384, 0, stream>>>(x, musum, msqsum);
  k_bn<<<NN, 64, 0, stream>>>(x, gamma, beta, musum, msqsum, h, h_bf, ninv);
  k_counts<<<NE / 256, 256, 0, stream>>>(ei, et, c_rel);
  k_scan<<<1, 1024, 0, stream>>>(c_rel, rp2, cursor);
  k_fill<<<NE / 256, 256, 0, stream>>>(ei, et, cursor, meta);
  k_we2<<<NN, 256, 0, stream>>>(h_bf, ninv, rp2, meta, wsort);
  k_packall<<<(NL * 384 * 1536 + NL * 384 * 768 + 255) / 256, 256, 0, stream>>>(
      W_rel, W_msg, W_self, Wcat, Wcat2);

  for (int l = 0; l < NL; ++l) {
    k_aggrel<<<NN, 384, 0, stream>>>(h_bf, rp2, meta, wsort, nc, Agg, SC, l);
    k_gemm_mfma<0><<<dim3(128, 6), 256, 0, stream>>>(
        Agg, 1536, Wcat + (size_t)l * 384 * 1536, SC, b_rel + l * NR * DD,
        nullptr, nullptr, nullptr, nullptr, nullptr, B1);
    k_aggmp<<<NN, 384, 0, stream>>>(B1, rp2, meta);
    k_gemm_mfma<1><<<dim3(128, 6), 256, 0, stream>>>(
        B1, 768, Wcat2 + (size_t)l * 384 * 768, nullptr, nullptr,
        b_msg + l * DD, b_self + l * DD, rp2, h, h_bf, nullptr);
  }
  k_out<<<64, 384, 0, stream>>>(h, out);
}